// Round 13
// baseline (210.489 us; speedup 1.0000x reference)
//
#include <hip/hip_runtime.h>
#include <hip/hip_bf16.h>
#include <math.h>

#define BB 8
#define SS 2048
#define HH 1024
#define DD 64
#define NCV 65

typedef __attribute__((ext_vector_type(8))) short bf16x8;
typedef __attribute__((ext_vector_type(4))) float f32x4;
typedef __attribute__((ext_vector_type(16))) float f32x16;

#define MFMA16(a, b, c) __builtin_amdgcn_mfma_f32_16x16x32_bf16(a, b, c, 0, 0, 0)
#define MFMA32(a, b, c) __builtin_amdgcn_mfma_f32_32x32x16_bf16(a, b, c, 0, 0, 0)

__device__ __forceinline__ ushort bf16rne(float f) {
    uint u = __float_as_uint(f);
    uint r = (u + 0x7FFFu + ((u >> 16) & 1u)) >> 16;
    return (ushort)r;
}
__device__ __forceinline__ ushort bfc(float f) {
    __hip_bfloat16 h = __float2bfloat16(f);
    return *reinterpret_cast<ushort*>(&h);
}
__device__ __forceinline__ float bf2f(ushort h) {
    return __uint_as_float(((uint)h) << 16);
}

// score = (1 + acos(clip(cos)))^-65.5
__device__ __forceinline__ float score_fn(float cosv) {
    float ax = fminf(fabsf(cosv), 1.0f - 1e-7f);
    float p = fmaf(ax, -0.0012624911f, 0.0066700901f);
    p = fmaf(ax, p, -0.0170881256f);
    p = fmaf(ax, p, 0.0308918810f);
    p = fmaf(ax, p, -0.0501743046f);
    p = fmaf(ax, p, 0.0889789874f);
    p = fmaf(ax, p, -0.2145988016f);
    p = fmaf(ax, p, 1.5707963050f);
    float r = sqrtf(1.0f - ax) * p;
    float g = (cosv >= 0.0f) ? r : (3.14159265358979f - r);
    return exp2f(-65.5f * log2f(1.0f + g));
}

// K0: split W into bf16 hi/lo.
__global__ __launch_bounds__(256) void k_prep(
    const float* __restrict__ Wq, const float* __restrict__ Wk, const float* __restrict__ Wv,
    const float* __restrict__ bq, const float* __restrict__ bk, const float* __restrict__ bv,
    ushort* __restrict__ Whi, ushort* __restrict__ Wlo, float* __restrict__ bcat)
{
    const int n = blockIdx.x;
    const int m = n >> 6, d = n & 63;
    const float* W = (m == 0) ? Wq : (m == 1 ? Wk : Wv);
    #pragma unroll
    for (int i = 0; i < 4; ++i) {
        int j = i * 256 + threadIdx.x;
        float f = W[(size_t)j * DD + d];
        ushort h = bf16rne(f);
        Whi[(size_t)n * HH + j] = h;
        Wlo[(size_t)n * HH + j] = bf16rne(f - bf2f(h));
    }
    if (n == 0 && threadIdx.x < 192) {
        int t = threadIdx.x, mm = t >> 6, dd = t & 63;
        const float* b = (mm == 0) ? bq : (mm == 1 ? bk : bv);
        bcat[t] = b[dd];
    }
}

// K1: q,k,v = l2norm(x @ W + b) via split-bf16 MFMA.
__global__ __launch_bounds__(256) void k_projmm(
    const float* __restrict__ x, const ushort* __restrict__ Whi,
    const ushort* __restrict__ Wlo, const float* __restrict__ bcat,
    ushort* __restrict__ qh, ushort* __restrict__ ql,
    ushort* __restrict__ kh, ushort* __restrict__ kl,
    float* __restrict__ vw)
{
    __shared__ __align__(16) char smem[32 * 193 * 4];
    __shared__ float rns[96];
    __shared__ float bsh[192];
    ushort* xhi = (ushort*)smem;
    ushort* xlo = xhi + 32 * 128;
    float* ctile = (float*)smem;

    const int t = threadIdx.x;
    const int lane = t & 63;
    const int wid = t >> 6;
    const int row0 = blockIdx.x * 32;
    if (t < 192) bsh[t] = bcat[t];

    f32x4 acc[2][3];
    #pragma unroll
    for (int ar = 0; ar < 2; ++ar)
        #pragma unroll
        for (int bc = 0; bc < 3; ++bc)
            acc[ar][bc] = (f32x4){0.f, 0.f, 0.f, 0.f};

    for (int ch = 0; ch < 8; ++ch) {
        const int j0 = ch * 128;
        __syncthreads();
        #pragma unroll
        for (int i = 0; i < 2; ++i) {
            int u = i * 256 + t;
            int row = u >> 4, uc = u & 15;
            const float* xp = &x[(size_t)(row0 + row) * HH + j0 + uc * 8];
            float4 a = *(const float4*)xp;
            float4 b = *(const float4*)(xp + 4);
            float fs[8] = {a.x, a.y, a.z, a.w, b.x, b.y, b.z, b.w};
            bf16x8 hv, lv;
            #pragma unroll
            for (int e = 0; e < 8; ++e) {
                ushort h = bf16rne(fs[e]);
                hv[e] = (short)h;
                lv[e] = (short)bf16rne(fs[e] - bf2f(h));
            }
            int su = uc ^ (row & 7);
            *(bf16x8*)(xhi + row * 128 + su * 8) = hv;
            *(bf16x8*)(xlo + row * 128 + su * 8) = lv;
        }
        __syncthreads();
        #pragma unroll
        for (int ks = 0; ks < 4; ++ks) {
            bf16x8 ah[2], al[2], bh[3], bl[3];
            #pragma unroll
            for (int ar = 0; ar < 2; ++ar) {
                int row = ar * 16 + (lane & 15);
                int su = (ks * 4 + (lane >> 4)) ^ (row & 7);
                ah[ar] = *(const bf16x8*)(xhi + row * 128 + su * 8);
                al[ar] = *(const bf16x8*)(xlo + row * 128 + su * 8);
            }
            const int koff = j0 + ks * 32 + (lane >> 4) * 8;
            #pragma unroll
            for (int bc = 0; bc < 3; ++bc) {
                int n = wid * 48 + bc * 16 + (lane & 15);
                bh[bc] = *(const bf16x8*)(Whi + (size_t)n * HH + koff);
                bl[bc] = *(const bf16x8*)(Wlo + (size_t)n * HH + koff);
            }
            #pragma unroll
            for (int ar = 0; ar < 2; ++ar)
                #pragma unroll
                for (int bc = 0; bc < 3; ++bc) {
                    acc[ar][bc] = MFMA16(ah[ar], bh[bc], acc[ar][bc]);
                    acc[ar][bc] = MFMA16(ah[ar], bl[bc], acc[ar][bc]);
                    acc[ar][bc] = MFMA16(al[ar], bh[bc], acc[ar][bc]);
                }
        }
    }
    __syncthreads();
    #pragma unroll
    for (int ar = 0; ar < 2; ++ar)
        #pragma unroll
        for (int bc = 0; bc < 3; ++bc) {
            int n = wid * 48 + bc * 16 + (lane & 15);
            #pragma unroll
            for (int r = 0; r < 4; ++r) {
                int row = ar * 16 + (lane >> 4) * 4 + r;
                ctile[row * 193 + n] = acc[ar][bc][r];
            }
        }
    __syncthreads();
    if (t < 96) {
        int mat = t >> 5, row = t & 31;
        float ss = 0.f;
        #pragma unroll 8
        for (int d = 0; d < 64; ++d) {
            float v = ctile[row * 193 + mat * 64 + d] + bsh[mat * 64 + d];
            ss = fmaf(v, v, ss);
        }
        rns[t] = 1.0f / fmaxf(sqrtf(ss), 1e-12f);
    }
    __syncthreads();
    #pragma unroll
    for (int i = 0; i < 24; ++i) {
        int idx = i * 256 + t;
        int row = idx / 192;
        int n = idx - row * 192;
        float v = (ctile[row * 193 + n] + bsh[n]) * rns[(n >> 6) * 32 + row];
        size_t off = (size_t)(row0 + row) * DD + (n & 63);
        if (n < 64) {
            ushort h = bf16rne(v);
            qh[off] = h; ql[off] = bf16rne(v - bf2f(h));
        } else if (n < 128) {
            ushort h = bf16rne(v);
            kh[off] = h; kl[off] = bf16rne(v - bf2f(h));
        } else {
            vw[off] = v;
        }
    }
}

// K2: score once. Per block: 32 q x 512 k (LDS 32KB), grid 8b*64qt*4ks = 2048.
// 32x32x16 MFMA, register double-buffer; LDS transpose; in-block colsum;
// coalesced 16B global stores. (R11 configuration — best measured.)
#define K_LOAD(H0,H1,H2,H3,L0,L1,L2,L3, KT) { \
    const ushort* kp = kh + (size_t)(b * SS + kbase + (KT) * 32 + qrow) * DD + kg; \
    const ushort* lp = kl + (size_t)(b * SS + kbase + (KT) * 32 + qrow) * DD + kg; \
    H0 = *(const bf16x8*)(kp);      L0 = *(const bf16x8*)(lp); \
    H1 = *(const bf16x8*)(kp + 16); L1 = *(const bf16x8*)(lp + 16); \
    H2 = *(const bf16x8*)(kp + 32); L2 = *(const bf16x8*)(lp + 32); \
    H3 = *(const bf16x8*)(kp + 48); L3 = *(const bf16x8*)(lp + 48); }

#define K_COMPUTE(H0,H1,H2,H3,L0,L1,L2,L3, KT) { \
    f32x16 acc = Z16; \
    acc = MFMA32(H0, qbh0, acc); acc = MFMA32(H0, qbl0, acc); acc = MFMA32(L0, qbh0, acc); \
    acc = MFMA32(H1, qbh1, acc); acc = MFMA32(H1, qbl1, acc); acc = MFMA32(L1, qbh1, acc); \
    acc = MFMA32(H2, qbh2, acc); acc = MFMA32(H2, qbl2, acc); acc = MFMA32(L2, qbh2, acc); \
    acc = MFMA32(H3, qbh3, acc); acc = MFMA32(H3, qbl3, acc); acc = MFMA32(L3, qbh3, acc); \
    const int kb = (w * 128 + (KT) * 32) * 2 + hi8; \
    uint2 wv; \
    wv.x = (uint)bfc(score_fn(acc[0]))  | ((uint)bfc(score_fn(acc[1]))  << 16); \
    wv.y = (uint)bfc(score_fn(acc[2]))  | ((uint)bfc(score_fn(acc[3]))  << 16); \
    *(uint2*)(ldsrow + ((kb +  0) ^ swq)) = wv; \
    wv.x = (uint)bfc(score_fn(acc[4]))  | ((uint)bfc(score_fn(acc[5]))  << 16); \
    wv.y = (uint)bfc(score_fn(acc[6]))  | ((uint)bfc(score_fn(acc[7]))  << 16); \
    *(uint2*)(ldsrow + ((kb + 16) ^ swq)) = wv; \
    wv.x = (uint)bfc(score_fn(acc[8]))  | ((uint)bfc(score_fn(acc[9]))  << 16); \
    wv.y = (uint)bfc(score_fn(acc[10])) | ((uint)bfc(score_fn(acc[11])) << 16); \
    *(uint2*)(ldsrow + ((kb + 32) ^ swq)) = wv; \
    wv.x = (uint)bfc(score_fn(acc[12])) | ((uint)bfc(score_fn(acc[13])) << 16); \
    wv.y = (uint)bfc(score_fn(acc[14])) | ((uint)bfc(score_fn(acc[15])) << 16); \
    *(uint2*)(ldsrow + ((kb + 48) ^ swq)) = wv; }

__global__ __launch_bounds__(256, 4) void k_score(
    const ushort* __restrict__ qh, const ushort* __restrict__ ql,
    const ushort* __restrict__ kh, const ushort* __restrict__ kl,
    ushort* __restrict__ scrS, float* __restrict__ colsum)
{
    __shared__ __align__(16) char slds[32 * 1024];   // [32 q][512 k] bf16, swizzled
    const int t = threadIdx.x;
    const int lane = t & 63;
    const int w = t >> 6;
    const int bid = blockIdx.x;
    const int b  = bid >> 8;
    const int q0 = ((bid >> 2) & 63) * 32;
    const int kgB = (bid & 3) * 512;
    const int kbase = kgB + w * 128;
    const int qrow = lane & 31;
    const int kg = (lane >> 5) * 8;
    const int hi8 = (lane >> 5) * 8;
    const int swq = (qrow & 15) << 3;
    char* ldsrow = slds + qrow * 1024;
    const f32x16 Z16 = {0.f,0.f,0.f,0.f,0.f,0.f,0.f,0.f,0.f,0.f,0.f,0.f,0.f,0.f,0.f,0.f};

    const size_t qoff = (size_t)(b * SS + q0 + qrow) * DD + kg;
    bf16x8 qbh0 = *(const bf16x8*)(qh + qoff);
    bf16x8 qbh1 = *(const bf16x8*)(qh + qoff + 16);
    bf16x8 qbh2 = *(const bf16x8*)(qh + qoff + 32);
    bf16x8 qbh3 = *(const bf16x8*)(qh + qoff + 48);
    bf16x8 qbl0 = *(const bf16x8*)(ql + qoff);
    bf16x8 qbl1 = *(const bf16x8*)(ql + qoff + 16);
    bf16x8 qbl2 = *(const bf16x8*)(ql + qoff + 32);
    bf16x8 qbl3 = *(const bf16x8*)(ql + qoff + 48);

    bf16x8 xh0, xh1, xh2, xh3, xl0, xl1, xl2, xl3;
    bf16x8 yh0, yh1, yh2, yh3, yl0, yl1, yl2, yl3;
    K_LOAD(xh0,xh1,xh2,xh3,xl0,xl1,xl2,xl3, 0)
    K_LOAD(yh0,yh1,yh2,yh3,yl0,yl1,yl2,yl3, 1)
    K_COMPUTE(xh0,xh1,xh2,xh3,xl0,xl1,xl2,xl3, 0)
    K_LOAD(xh0,xh1,xh2,xh3,xl0,xl1,xl2,xl3, 2)
    K_COMPUTE(yh0,yh1,yh2,yh3,yl0,yl1,yl2,yl3, 1)
    K_LOAD(yh0,yh1,yh2,yh3,yl0,yl1,yl2,yl3, 3)
    K_COMPUTE(xh0,xh1,xh2,xh3,xl0,xl1,xl2,xl3, 2)
    K_COMPUTE(yh0,yh1,yh2,yh3,yl0,yl1,yl2,yl3, 3)

    __syncthreads();
    // colsum over this block's 32 q rows: thread t handles k-local {2t, 2t+1}
    {
        float s0 = 0.f, s1 = 0.f;
        #pragma unroll 8
        for (int r = 0; r < 32; ++r) {
            uint d = *(const uint*)(slds + r * 1024 + ((t * 4) ^ ((r & 15) << 3)));
            s0 += bf2f((ushort)(d & 0xFFFFu));
            s1 += bf2f((ushort)(d >> 16));
        }
        atomicAdd(&colsum[b * SS + kgB + t * 2 + 0], s0);
        atomicAdd(&colsum[b * SS + kgB + t * 2 + 1], s1);
    }
    // coalesced global store: row r = t>>3, 8 threads/row, 16B chunks
    {
        const int r = t >> 3;
        const int swr = (r & 15) << 3;
        const char* lrow = slds + r * 1024;
        ushort* srowg = scrS + (size_t)(b * SS + q0 + r) * 4096 + 2048 + kgB;
        #pragma unroll
        for (int i = 0; i < 8; ++i) {
            int c = (t & 7) + i * 8;
            int lc = c * 16;
            uint2 a = *(const uint2*)(lrow + (lc ^ swr));
            uint2 bb = *(const uint2*)(lrow + ((lc + 8) ^ swr));
            uint4 v;
            v.x = a.x; v.y = a.y; v.z = bb.x; v.w = bb.y;
            *(uint4*)(srowg + c * 8) = v;
        }
    }
}

// K3b: c = colsum^-0.5; cvT build. Grid = 8b*32 = 256 blocks.
__global__ __launch_bounds__(256) void k_cvc(
    const float* __restrict__ vw, const float* __restrict__ colsum,
    ushort* __restrict__ cvT)
{
    __shared__ float vs[64][65];
    __shared__ float csh[64];
    const int t = threadIdx.x;
    const int b = blockIdx.x >> 5;
    const int k0 = (blockIdx.x & 31) * 64;
    #pragma unroll
    for (int i = 0; i < 4; ++i) {
        int idx = i * 256 + t;
        int r = idx >> 4, c4 = idx & 15;
        float4 v4 = *(const float4*)&vw[(size_t)(b * SS + k0 + r) * DD + c4 * 4];
        *(float4*)&vs[r][c4 * 4] = v4;
    }
    if (t < 64) csh[t] = 1.0f / sqrtf(colsum[b * SS + k0 + t]);
    __syncthreads();
    const int kk4 = (t & 15) * 4;
    #pragma unroll
    for (int jt = 0; jt < 4; ++jt) {
        int j = jt * 16 + (t >> 4);
        uint2 wv;
        wv.x = (uint)bfc(csh[kk4 + 0] * vs[kk4 + 0][j])
             | ((uint)bfc(csh[kk4 + 1] * vs[kk4 + 1][j]) << 16);
        wv.y = (uint)bfc(csh[kk4 + 2] * vs[kk4 + 2][j])
             | ((uint)bfc(csh[kk4 + 3] * vs[kk4 + 3][j]) << 16);
        *(uint2*)(cvT + ((size_t)b * NCV + j) * SS + k0 + kk4) = wv;
    }
    if (t < 16) {
        uint2 wv;
        wv.x = (uint)bfc(csh[t * 4 + 0]) | ((uint)bfc(csh[t * 4 + 1]) << 16);
        wv.y = (uint)bfc(csh[t * 4 + 2]) | ((uint)bfc(csh[t * 4 + 3]) << 16);
        *(uint2*)(cvT + ((size_t)b * NCV + 64) * SS + k0 + t * 4) = wv;
    }
}

// K4: N/D per 16 q-rows; out = N/D; dinv -> global. Grid = 1024, 256 thr (4 waves).
__global__ __launch_bounds__(256, 4) void k_nd(
    const ushort* __restrict__ scrS, const ushort* __restrict__ cvT,
    float* __restrict__ dinv_g, float* __restrict__ out)
{
    __shared__ float nred[16][64];
    __shared__ float dPart[4][16];
    __shared__ float dInv[16];
    const int t = threadIdx.x;
    const int lane = t & 63;
    const int w = t >> 6;
    const int b = blockIdx.x >> 7;
    const int q0 = (blockIdx.x & 127) * 16;
    const int kbase = w * 512;
    const int qn = lane & 15;
    const int g = lane >> 4;

    ((float*)nred)[t] = 0.f; ((float*)nred)[t + 256] = 0.f;
    ((float*)nred)[t + 512] = 0.f; ((float*)nred)[t + 768] = 0.f;
    __syncthreads();

    const ushort* cslice = cvT + (size_t)b * NCV * SS;
    const ushort* cbrow = cslice + (size_t)64 * SS;

    float dacc = 0.f;
    f32x4 nacc[4];
    #pragma unroll
    for (int ct = 0; ct < 4; ++ct) nacc[ct] = (f32x4){0.f, 0.f, 0.f, 0.f};

    const ushort* sp = scrS + (size_t)(b * SS + q0 + qn) * 4096 + 2048 + kbase + g * 8;
    const ushort* cp = cbrow + kbase + g * 8;
    const ushort* p0 = cslice + (size_t)(0 * 16 + qn) * SS + kbase + g * 8;
    const ushort* p1 = cslice + (size_t)(1 * 16 + qn) * SS + kbase + g * 8;
    const ushort* p2 = cslice + (size_t)(2 * 16 + qn) * SS + kbase + g * 8;
    const ushort* p3 = cslice + (size_t)(3 * 16 + qn) * SS + kbase + g * 8;

    #pragma unroll 4
    for (int ch = 0; ch < 16; ++ch) {
        bf16x8 s8 = *(const bf16x8*)sp;
        bf16x8 c8 = *(const bf16x8*)cp;
        bf16x8 b0 = *(const bf16x8*)p0;
        bf16x8 b1 = *(const bf16x8*)p1;
        bf16x8 b2 = *(const bf16x8*)p2;
        bf16x8 b3 = *(const bf16x8*)p3;
        #pragma unroll
        for (int e = 0; e < 8; ++e)
            dacc = fmaf(bf2f((ushort)s8[e]), bf2f((ushort)c8[e]), dacc);
        nacc[0] = MFMA16(s8, b0, nacc[0]);
        nacc[1] = MFMA16(s8, b1, nacc[1]);
        nacc[2] = MFMA16(s8, b2, nacc[2]);
        nacc[3] = MFMA16(s8, b3, nacc[3]);
        sp += 32; cp += 32; p0 += 32; p1 += 32; p2 += 32; p3 += 32;
    }
    {
        float d = dacc;
        d += __shfl_xor(d, 16, 64);
        d += __shfl_xor(d, 32, 64);
        if (lane < 16) dPart[w][lane] = d;
    }
    __syncthreads();
    if (t < 16) {
        float di = 1.0f / (dPart[0][t] + dPart[1][t] + dPart[2][t] + dPart[3][t]);
        dInv[t] = di;
        dinv_g[b * SS + q0 + t] = di;
    }
    #pragma unroll
    for (int ct = 0; ct < 4; ++ct)
        #pragma unroll
        for (int r = 0; r < 4; ++r)
            atomicAdd(&nred[g * 4 + r][ct * 16 + qn], nacc[ct][r]);
    __syncthreads();
    {
        int q = t >> 4, c4 = (t & 15) * 4;
        float di = dInv[q];
        float4 o;
        o.x = nred[q][c4] * di;     o.y = nred[q][c4 + 1] * di;
        o.z = nred[q][c4 + 2] * di; o.w = nred[q][c4 + 3] * di;
        *(float4*)&out[(size_t)(b * SS + q0 + q) * DD + c4] = o;
    }
}

// K5: probs = s*c*dInv, pure streaming, in-place expansion.
// Grid = 8b * 512 rowgroups(4 rows) = 4096 blocks, 256 thr. Load 4 rows to regs,
// ONE barrier (WAR), nontemporal f32 stores.
__global__ __launch_bounds__(256) void k_probs(
    const ushort* __restrict__ scrS, const ushort* __restrict__ cvT,
    const float* __restrict__ dinv_g, float* __restrict__ probs)
{
    const int t = threadIdx.x;
    const int b = blockIdx.x >> 9;
    const int r0 = (blockIdx.x & 511) * 4;
    const ushort* cbrow = cvT + ((size_t)b * NCV + 64) * SS;

    float cf[8];
    {
        bf16x8 c8 = *(const bf16x8*)(cbrow + t * 8);
        #pragma unroll
        for (int e = 0; e < 8; ++e) cf[e] = bf2f((ushort)c8[e]);
    }
    bf16x8 s[4];
    float dl[4];
    #pragma unroll
    for (int j = 0; j < 4; ++j) {
        s[j] = *(const bf16x8*)(scrS + (size_t)(b * SS + r0 + j) * 4096 + 2048 + t * 8);
        dl[j] = dinv_g[b * SS + r0 + j];
    }
    __syncthreads();   // all reads of these 4 rows done before their writes
    #pragma unroll
    for (int j = 0; j < 4; ++j) {
        f32x4 o0, o1;
        o0[0] = bf2f((ushort)s[j][0]) * cf[0] * dl[j];
        o0[1] = bf2f((ushort)s[j][1]) * cf[1] * dl[j];
        o0[2] = bf2f((ushort)s[j][2]) * cf[2] * dl[j];
        o0[3] = bf2f((ushort)s[j][3]) * cf[3] * dl[j];
        o1[0] = bf2f((ushort)s[j][4]) * cf[4] * dl[j];
        o1[1] = bf2f((ushort)s[j][5]) * cf[5] * dl[j];
        o1[2] = bf2f((ushort)s[j][6]) * cf[6] * dl[j];
        o1[3] = bf2f((ushort)s[j][7]) * cf[7] * dl[j];
        float* prow = probs + (size_t)(b * SS + r0 + j) * SS + t * 8;
        __builtin_nontemporal_store(o0, (f32x4*)prow);
        __builtin_nontemporal_store(o1, (f32x4*)(prow + 4));
    }
}

extern "C" void kernel_launch(void* const* d_in, const int* in_sizes, int n_in,
                              void* d_out, int out_size, void* d_ws, size_t ws_size,
                              hipStream_t stream)
{
    const float* x  = (const float*)d_in[0];
    const float* Wq = (const float*)d_in[1];
    const float* bq = (const float*)d_in[2];
    const float* Wk = (const float*)d_in[3];
    const float* bk = (const float*)d_in[4];
    const float* Wv = (const float*)d_in[5];
    const float* bv = (const float*)d_in[6];

    float* out   = (float*)d_out;                       // [8,2048,64]
    float* probs = out + (size_t)BB * SS * DD;          // [8,2048,2048]
    ushort* scrS = (ushort*)probs;                      // score bf16 in row upper halves

    const size_t NQ = (size_t)BB * SS * DD;
    ushort* qh    = (ushort*)d_ws;
    ushort* ql    = qh + NQ;
    ushort* kh    = ql + NQ;
    ushort* kl    = kh + NQ;
    float*  vw    = (float*)(kl + NQ);
    float*  colsum = vw + NQ;
    float*  dinv  = colsum + BB * SS;
    ushort* cvT   = (ushort*)(dinv + BB * SS);
    ushort* Whi   = cvT + (size_t)BB * NCV * SS;
    ushort* Wlo   = Whi + (size_t)192 * HH;
    float*  bcat  = (float*)(Wlo + (size_t)192 * HH);

    hipMemsetAsync(colsum, 0, BB * SS * sizeof(float), stream);
    k_prep  <<<192, 256, 0, stream>>>(Wq, Wk, Wv, bq, bk, bv, Whi, Wlo, bcat);
    k_projmm<<<512, 256, 0, stream>>>(x, Whi, Wlo, bcat, qh, ql, kh, kl, vw);
    k_score <<<2048, 256, 0, stream>>>(qh, ql, kh, kl, scrS, colsum);
    k_cvc   <<<256, 256, 0, stream>>>(vw, colsum, cvT);
    k_nd    <<<1024, 256, 0, stream>>>(scrS, cvT, dinv, out);
    k_probs <<<4096, 256, 0, stream>>>(scrS, cvT, dinv, probs);
}

// Round 14
// 208.902 us; speedup vs baseline: 1.0076x; 1.0076x over previous
//
#include <hip/hip_runtime.h>
#include <hip/hip_bf16.h>
#include <math.h>

#define BB 8
#define SS 2048
#define HH 1024
#define DD 64
#define NCV 80

typedef __attribute__((ext_vector_type(8))) short bf16x8;
typedef __attribute__((ext_vector_type(4))) float f32x4;
typedef __attribute__((ext_vector_type(16))) float f32x16;

#define MFMA16(a, b, c) __builtin_amdgcn_mfma_f32_16x16x32_bf16(a, b, c, 0, 0, 0)
#define MFMA32(a, b, c) __builtin_amdgcn_mfma_f32_32x32x16_bf16(a, b, c, 0, 0, 0)

__device__ __forceinline__ ushort bf16rne(float f) {
    uint u = __float_as_uint(f);
    uint r = (u + 0x7FFFu + ((u >> 16) & 1u)) >> 16;
    return (ushort)r;
}
__device__ __forceinline__ ushort bfc(float f) {
    __hip_bfloat16 h = __float2bfloat16(f);
    return *reinterpret_cast<ushort*>(&h);
}
__device__ __forceinline__ float bf2f(ushort h) {
    return __uint_as_float(((uint)h) << 16);
}

// score = (1 + acos(clip(cos)))^-65.5
__device__ __forceinline__ float score_fn(float cosv) {
    float ax = fminf(fabsf(cosv), 1.0f - 1e-7f);
    float p = fmaf(ax, -0.0012624911f, 0.0066700901f);
    p = fmaf(ax, p, -0.0170881256f);
    p = fmaf(ax, p, 0.0308918810f);
    p = fmaf(ax, p, -0.0501743046f);
    p = fmaf(ax, p, 0.0889789874f);
    p = fmaf(ax, p, -0.2145988016f);
    p = fmaf(ax, p, 1.5707963050f);
    float r = sqrtf(1.0f - ax) * p;
    float g = (cosv >= 0.0f) ? r : (3.14159265358979f - r);
    return exp2f(-65.5f * log2f(1.0f + g));
}

// K0: split W into bf16 hi/lo.
__global__ __launch_bounds__(256) void k_prep(
    const float* __restrict__ Wq, const float* __restrict__ Wk, const float* __restrict__ Wv,
    const float* __restrict__ bq, const float* __restrict__ bk, const float* __restrict__ bv,
    ushort* __restrict__ Whi, ushort* __restrict__ Wlo, float* __restrict__ bcat)
{
    const int n = blockIdx.x;
    const int m = n >> 6, d = n & 63;
    const float* W = (m == 0) ? Wq : (m == 1 ? Wk : Wv);
    #pragma unroll
    for (int i = 0; i < 4; ++i) {
        int j = i * 256 + threadIdx.x;
        float f = W[(size_t)j * DD + d];
        ushort h = bf16rne(f);
        Whi[(size_t)n * HH + j] = h;
        Wlo[(size_t)n * HH + j] = bf16rne(f - bf2f(h));
    }
    if (n == 0 && threadIdx.x < 192) {
        int t = threadIdx.x, mm = t >> 6, dd = t & 63;
        const float* b = (mm == 0) ? bq : (mm == 1 ? bk : bv);
        bcat[t] = b[dd];
    }
}

// K1: q,k,v = l2norm(x @ W + b) via split-bf16 MFMA.
__global__ __launch_bounds__(256) void k_projmm(
    const float* __restrict__ x, const ushort* __restrict__ Whi,
    const ushort* __restrict__ Wlo, const float* __restrict__ bcat,
    ushort* __restrict__ qh, ushort* __restrict__ ql,
    ushort* __restrict__ kh, ushort* __restrict__ kl,
    float* __restrict__ vw)
{
    __shared__ __align__(16) char smem[32 * 193 * 4];
    __shared__ float rns[96];
    __shared__ float bsh[192];
    ushort* xhi = (ushort*)smem;
    ushort* xlo = xhi + 32 * 128;
    float* ctile = (float*)smem;

    const int t = threadIdx.x;
    const int lane = t & 63;
    const int wid = t >> 6;
    const int row0 = blockIdx.x * 32;
    if (t < 192) bsh[t] = bcat[t];

    f32x4 acc[2][3];
    #pragma unroll
    for (int ar = 0; ar < 2; ++ar)
        #pragma unroll
        for (int bc = 0; bc < 3; ++bc)
            acc[ar][bc] = (f32x4){0.f, 0.f, 0.f, 0.f};

    for (int ch = 0; ch < 8; ++ch) {
        const int j0 = ch * 128;
        __syncthreads();
        #pragma unroll
        for (int i = 0; i < 2; ++i) {
            int u = i * 256 + t;
            int row = u >> 4, uc = u & 15;
            const float* xp = &x[(size_t)(row0 + row) * HH + j0 + uc * 8];
            float4 a = *(const float4*)xp;
            float4 b = *(const float4*)(xp + 4);
            float fs[8] = {a.x, a.y, a.z, a.w, b.x, b.y, b.z, b.w};
            bf16x8 hv, lv;
            #pragma unroll
            for (int e = 0; e < 8; ++e) {
                ushort h = bf16rne(fs[e]);
                hv[e] = (short)h;
                lv[e] = (short)bf16rne(fs[e] - bf2f(h));
            }
            int su = uc ^ (row & 7);
            *(bf16x8*)(xhi + row * 128 + su * 8) = hv;
            *(bf16x8*)(xlo + row * 128 + su * 8) = lv;
        }
        __syncthreads();
        #pragma unroll
        for (int ks = 0; ks < 4; ++ks) {
            bf16x8 ah[2], al[2], bh[3], bl[3];
            #pragma unroll
            for (int ar = 0; ar < 2; ++ar) {
                int row = ar * 16 + (lane & 15);
                int su = (ks * 4 + (lane >> 4)) ^ (row & 7);
                ah[ar] = *(const bf16x8*)(xhi + row * 128 + su * 8);
                al[ar] = *(const bf16x8*)(xlo + row * 128 + su * 8);
            }
            const int koff = j0 + ks * 32 + (lane >> 4) * 8;
            #pragma unroll
            for (int bc = 0; bc < 3; ++bc) {
                int n = wid * 48 + bc * 16 + (lane & 15);
                bh[bc] = *(const bf16x8*)(Whi + (size_t)n * HH + koff);
                bl[bc] = *(const bf16x8*)(Wlo + (size_t)n * HH + koff);
            }
            #pragma unroll
            for (int ar = 0; ar < 2; ++ar)
                #pragma unroll
                for (int bc = 0; bc < 3; ++bc) {
                    acc[ar][bc] = MFMA16(ah[ar], bh[bc], acc[ar][bc]);
                    acc[ar][bc] = MFMA16(ah[ar], bl[bc], acc[ar][bc]);
                    acc[ar][bc] = MFMA16(al[ar], bh[bc], acc[ar][bc]);
                }
        }
    }
    __syncthreads();
    #pragma unroll
    for (int ar = 0; ar < 2; ++ar)
        #pragma unroll
        for (int bc = 0; bc < 3; ++bc) {
            int n = wid * 48 + bc * 16 + (lane & 15);
            #pragma unroll
            for (int r = 0; r < 4; ++r) {
                int row = ar * 16 + (lane >> 4) * 4 + r;
                ctile[row * 193 + n] = acc[ar][bc][r];
            }
        }
    __syncthreads();
    if (t < 96) {
        int mat = t >> 5, row = t & 31;
        float ss = 0.f;
        #pragma unroll 8
        for (int d = 0; d < 64; ++d) {
            float v = ctile[row * 193 + mat * 64 + d] + bsh[mat * 64 + d];
            ss = fmaf(v, v, ss);
        }
        rns[t] = 1.0f / fmaxf(sqrtf(ss), 1e-12f);
    }
    __syncthreads();
    #pragma unroll
    for (int i = 0; i < 24; ++i) {
        int idx = i * 256 + t;
        int row = idx / 192;
        int n = idx - row * 192;
        float v = (ctile[row * 193 + n] + bsh[n]) * rns[(n >> 6) * 32 + row];
        size_t off = (size_t)(row0 + row) * DD + (n & 63);
        if (n < 64) {
            ushort h = bf16rne(v);
            qh[off] = h; ql[off] = bf16rne(v - bf2f(h));
        } else if (n < 128) {
            ushort h = bf16rne(v);
            kh[off] = h; kl[off] = bf16rne(v - bf2f(h));
        } else {
            vw[off] = v;
        }
    }
}

// K2: score once. Per block: 32 q x 512 k (LDS 32KB), grid 8b*64qt*4ks = 2048.
// (R11 configuration — best measured.)
#define K_LOAD(H0,H1,H2,H3,L0,L1,L2,L3, KT) { \
    const ushort* kp = kh + (size_t)(b * SS + kbase + (KT) * 32 + qrow) * DD + kg; \
    const ushort* lp = kl + (size_t)(b * SS + kbase + (KT) * 32 + qrow) * DD + kg; \
    H0 = *(const bf16x8*)(kp);      L0 = *(const bf16x8*)(lp); \
    H1 = *(const bf16x8*)(kp + 16); L1 = *(const bf16x8*)(lp + 16); \
    H2 = *(const bf16x8*)(kp + 32); L2 = *(const bf16x8*)(lp + 32); \
    H3 = *(const bf16x8*)(kp + 48); L3 = *(const bf16x8*)(lp + 48); }

#define K_COMPUTE(H0,H1,H2,H3,L0,L1,L2,L3, KT) { \
    f32x16 acc = Z16; \
    acc = MFMA32(H0, qbh0, acc); acc = MFMA32(H0, qbl0, acc); acc = MFMA32(L0, qbh0, acc); \
    acc = MFMA32(H1, qbh1, acc); acc = MFMA32(H1, qbl1, acc); acc = MFMA32(L1, qbh1, acc); \
    acc = MFMA32(H2, qbh2, acc); acc = MFMA32(H2, qbl2, acc); acc = MFMA32(L2, qbh2, acc); \
    acc = MFMA32(H3, qbh3, acc); acc = MFMA32(H3, qbl3, acc); acc = MFMA32(L3, qbh3, acc); \
    const int kb = (w * 128 + (KT) * 32) * 2 + hi8; \
    uint2 wv; \
    wv.x = (uint)bfc(score_fn(acc[0]))  | ((uint)bfc(score_fn(acc[1]))  << 16); \
    wv.y = (uint)bfc(score_fn(acc[2]))  | ((uint)bfc(score_fn(acc[3]))  << 16); \
    *(uint2*)(ldsrow + ((kb +  0) ^ swq)) = wv; \
    wv.x = (uint)bfc(score_fn(acc[4]))  | ((uint)bfc(score_fn(acc[5]))  << 16); \
    wv.y = (uint)bfc(score_fn(acc[6]))  | ((uint)bfc(score_fn(acc[7]))  << 16); \
    *(uint2*)(ldsrow + ((kb + 16) ^ swq)) = wv; \
    wv.x = (uint)bfc(score_fn(acc[8]))  | ((uint)bfc(score_fn(acc[9]))  << 16); \
    wv.y = (uint)bfc(score_fn(acc[10])) | ((uint)bfc(score_fn(acc[11])) << 16); \
    *(uint2*)(ldsrow + ((kb + 32) ^ swq)) = wv; \
    wv.x = (uint)bfc(score_fn(acc[12])) | ((uint)bfc(score_fn(acc[13])) << 16); \
    wv.y = (uint)bfc(score_fn(acc[14])) | ((uint)bfc(score_fn(acc[15])) << 16); \
    *(uint2*)(ldsrow + ((kb + 48) ^ swq)) = wv; }

__global__ __launch_bounds__(256, 4) void k_score(
    const ushort* __restrict__ qh, const ushort* __restrict__ ql,
    const ushort* __restrict__ kh, const ushort* __restrict__ kl,
    ushort* __restrict__ scrS, float* __restrict__ colsum)
{
    __shared__ __align__(16) char slds[32 * 1024];   // [32 q][512 k] bf16, swizzled
    const int t = threadIdx.x;
    const int lane = t & 63;
    const int w = t >> 6;
    const int bid = blockIdx.x;
    const int b  = bid >> 8;
    const int q0 = ((bid >> 2) & 63) * 32;
    const int kgB = (bid & 3) * 512;
    const int kbase = kgB + w * 128;
    const int qrow = lane & 31;
    const int kg = (lane >> 5) * 8;
    const int hi8 = (lane >> 5) * 8;
    const int swq = (qrow & 15) << 3;
    char* ldsrow = slds + qrow * 1024;
    const f32x16 Z16 = {0.f,0.f,0.f,0.f,0.f,0.f,0.f,0.f,0.f,0.f,0.f,0.f,0.f,0.f,0.f,0.f};

    const size_t qoff = (size_t)(b * SS + q0 + qrow) * DD + kg;
    bf16x8 qbh0 = *(const bf16x8*)(qh + qoff);
    bf16x8 qbh1 = *(const bf16x8*)(qh + qoff + 16);
    bf16x8 qbh2 = *(const bf16x8*)(qh + qoff + 32);
    bf16x8 qbh3 = *(const bf16x8*)(qh + qoff + 48);
    bf16x8 qbl0 = *(const bf16x8*)(ql + qoff);
    bf16x8 qbl1 = *(const bf16x8*)(ql + qoff + 16);
    bf16x8 qbl2 = *(const bf16x8*)(ql + qoff + 32);
    bf16x8 qbl3 = *(const bf16x8*)(ql + qoff + 48);

    bf16x8 xh0, xh1, xh2, xh3, xl0, xl1, xl2, xl3;
    bf16x8 yh0, yh1, yh2, yh3, yl0, yl1, yl2, yl3;
    K_LOAD(xh0,xh1,xh2,xh3,xl0,xl1,xl2,xl3, 0)
    K_LOAD(yh0,yh1,yh2,yh3,yl0,yl1,yl2,yl3, 1)
    K_COMPUTE(xh0,xh1,xh2,xh3,xl0,xl1,xl2,xl3, 0)
    K_LOAD(xh0,xh1,xh2,xh3,xl0,xl1,xl2,xl3, 2)
    K_COMPUTE(yh0,yh1,yh2,yh3,yl0,yl1,yl2,yl3, 1)
    K_LOAD(yh0,yh1,yh2,yh3,yl0,yl1,yl2,yl3, 3)
    K_COMPUTE(xh0,xh1,xh2,xh3,xl0,xl1,xl2,xl3, 2)
    K_COMPUTE(yh0,yh1,yh2,yh3,yl0,yl1,yl2,yl3, 3)

    __syncthreads();
    // colsum over this block's 32 q rows: thread t handles k-local {2t, 2t+1}
    {
        float s0 = 0.f, s1 = 0.f;
        #pragma unroll 8
        for (int r = 0; r < 32; ++r) {
            uint d = *(const uint*)(slds + r * 1024 + ((t * 4) ^ ((r & 15) << 3)));
            s0 += bf2f((ushort)(d & 0xFFFFu));
            s1 += bf2f((ushort)(d >> 16));
        }
        atomicAdd(&colsum[b * SS + kgB + t * 2 + 0], s0);
        atomicAdd(&colsum[b * SS + kgB + t * 2 + 1], s1);
    }
    // coalesced global store: row r = t>>3, 8 threads/row, 16B chunks
    {
        const int r = t >> 3;
        const int swr = (r & 15) << 3;
        const char* lrow = slds + r * 1024;
        ushort* srowg = scrS + (size_t)(b * SS + q0 + r) * 4096 + 2048 + kgB;
        #pragma unroll
        for (int i = 0; i < 8; ++i) {
            int c = (t & 7) + i * 8;
            int lc = c * 16;
            uint2 a = *(const uint2*)(lrow + (lc ^ swr));
            uint2 bb = *(const uint2*)(lrow + ((lc + 8) ^ swr));
            uint4 v;
            v.x = a.x; v.y = a.y; v.z = bb.x; v.w = bb.y;
            *(uint4*)(srowg + c * 8) = v;
        }
    }
}

// K3b: c = colsum^-0.5; cvT rows 0..63 = c*v^T, row 64 = c, rows 65..79 = 0.
// Grid = 8b*32 = 256 blocks.
__global__ __launch_bounds__(256) void k_cvc(
    const float* __restrict__ vw, const float* __restrict__ colsum,
    ushort* __restrict__ cvT)
{
    __shared__ float vs[64][65];
    __shared__ float csh[64];
    const int t = threadIdx.x;
    const int b = blockIdx.x >> 5;
    const int k0 = (blockIdx.x & 31) * 64;
    #pragma unroll
    for (int i = 0; i < 4; ++i) {
        int idx = i * 256 + t;
        int r = idx >> 4, c4 = idx & 15;
        float4 v4 = *(const float4*)&vw[(size_t)(b * SS + k0 + r) * DD + c4 * 4];
        *(float4*)&vs[r][c4 * 4] = v4;
    }
    if (t < 64) csh[t] = 1.0f / sqrtf(colsum[b * SS + k0 + t]);
    __syncthreads();
    const int kk4 = (t & 15) * 4;
    #pragma unroll
    for (int jt = 0; jt < 4; ++jt) {
        int j = jt * 16 + (t >> 4);
        uint2 wv;
        wv.x = (uint)bfc(csh[kk4 + 0] * vs[kk4 + 0][j])
             | ((uint)bfc(csh[kk4 + 1] * vs[kk4 + 1][j]) << 16);
        wv.y = (uint)bfc(csh[kk4 + 2] * vs[kk4 + 2][j])
             | ((uint)bfc(csh[kk4 + 3] * vs[kk4 + 3][j]) << 16);
        *(uint2*)(cvT + ((size_t)b * NCV + j) * SS + k0 + kk4) = wv;
    }
    if (t < 16) {
        uint2 wv;
        wv.x = (uint)bfc(csh[t * 4 + 0]) | ((uint)bfc(csh[t * 4 + 1]) << 16);
        wv.y = (uint)bfc(csh[t * 4 + 2]) | ((uint)bfc(csh[t * 4 + 3]) << 16);
        *(uint2*)(cvT + ((size_t)b * NCV + 64) * SS + k0 + t * 4) = wv;
    }
    // zero pad rows 65..79 (so D-via-MFMA's extra columns are exactly 0)
    if (t < 240) {
        int j = 65 + (t >> 4);
        uint2 z; z.x = 0u; z.y = 0u;
        *(uint2*)(cvT + ((size_t)b * NCV + j) * SS + k0 + kk4) = z;
    }
}

// K4: fused N/D + probs per 16 q-rows. Grid = 8b*128qt = 1024, 256 thr (4 waves).
// Phase A: stream score rows; 5 MFMA per chunk — 5th B-frag (cvT rows 64..79)
// computes D = N[:,64] via matrix pipe (no scalar chain, no unpack VALU).
// Phase B: probs in 4-row register batches; nontemporal stores.
__global__ __launch_bounds__(256, 4) void k_ndp(
    const ushort* __restrict__ scrS, const ushort* __restrict__ cvT,
    float* __restrict__ probs, float* __restrict__ out)
{
    __shared__ float nred[16][80];     // 5 KB; col 64 = D
    __shared__ float dInv[16];
    const int t = threadIdx.x;
    const int lane = t & 63;
    const int b = blockIdx.x >> 7;
    const int q0 = (blockIdx.x & 127) * 16;
    const int kbase = (t >> 6) * 512;
    const int qn = lane & 15;
    const int g = lane >> 4;

    #pragma unroll
    for (int i = 0; i < 5; ++i) ((float*)nred)[t + i * 256] = 0.f;
    __syncthreads();

    const ushort* cslice = cvT + (size_t)b * NCV * SS;
    const ushort* cbrow = cslice + (size_t)64 * SS;

    f32x4 nacc[5];
    #pragma unroll
    for (int ct = 0; ct < 5; ++ct) nacc[ct] = (f32x4){0.f, 0.f, 0.f, 0.f};

    const ushort* sp = scrS + (size_t)(b * SS + q0 + qn) * 4096 + 2048 + kbase + g * 8;
    const ushort* p0 = cslice + (size_t)(0 * 16 + qn) * SS + kbase + g * 8;
    const ushort* p1 = cslice + (size_t)(1 * 16 + qn) * SS + kbase + g * 8;
    const ushort* p2 = cslice + (size_t)(2 * 16 + qn) * SS + kbase + g * 8;
    const ushort* p3 = cslice + (size_t)(3 * 16 + qn) * SS + kbase + g * 8;
    const ushort* p4 = cslice + (size_t)(4 * 16 + qn) * SS + kbase + g * 8;  // rows 64..79

    #pragma unroll 4
    for (int ch = 0; ch < 16; ++ch) {
        bf16x8 s8 = *(const bf16x8*)sp;
        bf16x8 b0 = *(const bf16x8*)p0;
        bf16x8 b1 = *(const bf16x8*)p1;
        bf16x8 b2 = *(const bf16x8*)p2;
        bf16x8 b3 = *(const bf16x8*)p3;
        bf16x8 b4 = *(const bf16x8*)p4;
        nacc[0] = MFMA16(s8, b0, nacc[0]);
        nacc[1] = MFMA16(s8, b1, nacc[1]);
        nacc[2] = MFMA16(s8, b2, nacc[2]);
        nacc[3] = MFMA16(s8, b3, nacc[3]);
        nacc[4] = MFMA16(s8, b4, nacc[4]);
        sp += 32; p0 += 32; p1 += 32; p2 += 32; p3 += 32; p4 += 32;
    }
    // cross-wave N (and D, col 64) reduce
    #pragma unroll
    for (int ct = 0; ct < 5; ++ct)
        #pragma unroll
        for (int r = 0; r < 4; ++r)
            atomicAdd(&nred[g * 4 + r][ct * 16 + qn], nacc[ct][r]);
    __syncthreads();
    if (t < 16) dInv[t] = 1.0f / nred[t][64];
    __syncthreads();
    {
        int q = t >> 4, c4 = (t & 15) * 4;
        float di = dInv[q];
        float4 o;
        o.x = nred[q][c4] * di;     o.y = nred[q][c4 + 1] * di;
        o.z = nred[q][c4 + 2] * di; o.w = nred[q][c4 + 3] * di;
        *(float4*)&out[(size_t)(b * SS + q0 + q) * DD + c4] = o;
    }
    // Phase B: probs = s*c*dInv. 4-row register batches; thread t covers k=t*8..+7.
    float cf[8];
    {
        bf16x8 c8 = *(const bf16x8*)(cbrow + t * 8);
        #pragma unroll
        for (int e = 0; e < 8; ++e) cf[e] = bf2f((ushort)c8[e]);
    }
    #pragma unroll
    for (int rb = 0; rb < 4; ++rb) {
        bf16x8 s[4];
        float dl[4];
        #pragma unroll
        for (int j = 0; j < 4; ++j) {
            int row = rb * 4 + j;
            s[j] = *(const bf16x8*)(scrS + (size_t)(b * SS + q0 + row) * 4096 + 2048 + t * 8);
            dl[j] = dInv[row];
        }
        __syncthreads();   // all reads of these 4 rows done before their writes
        #pragma unroll
        for (int j = 0; j < 4; ++j) {
            f32x4 o0, o1;
            o0[0] = bf2f((ushort)s[j][0]) * cf[0] * dl[j];
            o0[1] = bf2f((ushort)s[j][1]) * cf[1] * dl[j];
            o0[2] = bf2f((ushort)s[j][2]) * cf[2] * dl[j];
            o0[3] = bf2f((ushort)s[j][3]) * cf[3] * dl[j];
            o1[0] = bf2f((ushort)s[j][4]) * cf[4] * dl[j];
            o1[1] = bf2f((ushort)s[j][5]) * cf[5] * dl[j];
            o1[2] = bf2f((ushort)s[j][6]) * cf[6] * dl[j];
            o1[3] = bf2f((ushort)s[j][7]) * cf[7] * dl[j];
            float* prow = probs + (size_t)(b * SS + q0 + rb * 4 + j) * SS + t * 8;
            __builtin_nontemporal_store(o0, (f32x4*)prow);
            __builtin_nontemporal_store(o1, (f32x4*)(prow + 4));
        }
    }
}

extern "C" void kernel_launch(void* const* d_in, const int* in_sizes, int n_in,
                              void* d_out, int out_size, void* d_ws, size_t ws_size,
                              hipStream_t stream)
{
    const float* x  = (const float*)d_in[0];
    const float* Wq = (const float*)d_in[1];
    const float* bq = (const float*)d_in[2];
    const float* Wk = (const float*)d_in[3];
    const float* bk = (const float*)d_in[4];
    const float* Wv = (const float*)d_in[5];
    const float* bv = (const float*)d_in[6];

    float* out   = (float*)d_out;                       // [8,2048,64]
    float* probs = out + (size_t)BB * SS * DD;          // [8,2048,2048]
    ushort* scrS = (ushort*)probs;                      // score bf16 in row upper halves

    const size_t NQ = (size_t)BB * SS * DD;
    ushort* qh    = (ushort*)d_ws;
    ushort* ql    = qh + NQ;
    ushort* kh    = ql + NQ;
    ushort* kl    = kh + NQ;
    float*  vw    = (float*)(kl + NQ);
    float*  colsum = vw + NQ;
    ushort* cvT   = (ushort*)(colsum + BB * SS);
    ushort* Whi   = cvT + (size_t)BB * NCV * SS;
    ushort* Wlo   = Whi + (size_t)192 * HH;
    float*  bcat  = (float*)(Wlo + (size_t)192 * HH);

    hipMemsetAsync(colsum, 0, BB * SS * sizeof(float), stream);
    k_prep  <<<192, 256, 0, stream>>>(Wq, Wk, Wv, bq, bk, bv, Whi, Wlo, bcat);
    k_projmm<<<512, 256, 0, stream>>>(x, Whi, Wlo, bcat, qh, ql, kh, kl, vw);
    k_score <<<2048, 256, 0, stream>>>(qh, ql, kh, kl, scrS, colsum);
    k_cvc   <<<256, 256, 0, stream>>>(vw, colsum, cvT);
    k_ndp   <<<1024, 256, 0, stream>>>(scrS, cvT, probs, out);
}

// Round 15
// 196.763 us; speedup vs baseline: 1.0698x; 1.0617x over previous
//
#include <hip/hip_runtime.h>
#include <hip/hip_bf16.h>
#include <math.h>

#define BB 8
#define SS 2048
#define HH 1024
#define DD 64
#define NCV 65

typedef __attribute__((ext_vector_type(8))) short bf16x8;
typedef __attribute__((ext_vector_type(4))) float f32x4;
typedef __attribute__((ext_vector_type(16))) float f32x16;

#define MFMA16(a, b, c) __builtin_amdgcn_mfma_f32_16x16x32_bf16(a, b, c, 0, 0, 0)
#define MFMA32(a, b, c) __builtin_amdgcn_mfma_f32_32x32x16_bf16(a, b, c, 0, 0, 0)

__device__ __forceinline__ ushort bf16rne(float f) {
    uint u = __float_as_uint(f);
    uint r = (u + 0x7FFFu + ((u >> 16) & 1u)) >> 16;
    return (ushort)r;
}
__device__ __forceinline__ ushort bfc(float f) {
    __hip_bfloat16 h = __float2bfloat16(f);
    return *reinterpret_cast<ushort*>(&h);
}
__device__ __forceinline__ float bf2f(ushort h) {
    return __uint_as_float(((uint)h) << 16);
}

// score = (1 + acos(clip(cos)))^-65.5
__device__ __forceinline__ float score_fn(float cosv) {
    float ax = fminf(fabsf(cosv), 1.0f - 1e-7f);
    float p = fmaf(ax, -0.0012624911f, 0.0066700901f);
    p = fmaf(ax, p, -0.0170881256f);
    p = fmaf(ax, p, 0.0308918810f);
    p = fmaf(ax, p, -0.0501743046f);
    p = fmaf(ax, p, 0.0889789874f);
    p = fmaf(ax, p, -0.2145988016f);
    p = fmaf(ax, p, 1.5707963050f);
    float r = sqrtf(1.0f - ax) * p;
    float g = (cosv >= 0.0f) ? r : (3.14159265358979f - r);
    return exp2f(-65.5f * log2f(1.0f + g));
}

// K0: split W into bf16 hi/lo.
__global__ __launch_bounds__(256) void k_prep(
    const float* __restrict__ Wq, const float* __restrict__ Wk, const float* __restrict__ Wv,
    const float* __restrict__ bq, const float* __restrict__ bk, const float* __restrict__ bv,
    ushort* __restrict__ Whi, ushort* __restrict__ Wlo, float* __restrict__ bcat)
{
    const int n = blockIdx.x;
    const int m = n >> 6, d = n & 63;
    const float* W = (m == 0) ? Wq : (m == 1 ? Wk : Wv);
    #pragma unroll
    for (int i = 0; i < 4; ++i) {
        int j = i * 256 + threadIdx.x;
        float f = W[(size_t)j * DD + d];
        ushort h = bf16rne(f);
        Whi[(size_t)n * HH + j] = h;
        Wlo[(size_t)n * HH + j] = bf16rne(f - bf2f(h));
    }
    if (n == 0 && threadIdx.x < 192) {
        int t = threadIdx.x, mm = t >> 6, dd = t & 63;
        const float* b = (mm == 0) ? bq : (mm == 1 ? bk : bv);
        bcat[t] = b[dd];
    }
}

// K1: q,k,v = l2norm(x @ W + b) via split-bf16 MFMA.
__global__ __launch_bounds__(256) void k_projmm(
    const float* __restrict__ x, const ushort* __restrict__ Whi,
    const ushort* __restrict__ Wlo, const float* __restrict__ bcat,
    ushort* __restrict__ qh, ushort* __restrict__ ql,
    ushort* __restrict__ kh, ushort* __restrict__ kl,
    float* __restrict__ vw)
{
    __shared__ __align__(16) char smem[32 * 193 * 4];
    __shared__ float rns[96];
    __shared__ float bsh[192];
    ushort* xhi = (ushort*)smem;
    ushort* xlo = xhi + 32 * 128;
    float* ctile = (float*)smem;

    const int t = threadIdx.x;
    const int lane = t & 63;
    const int wid = t >> 6;
    const int row0 = blockIdx.x * 32;
    if (t < 192) bsh[t] = bcat[t];

    f32x4 acc[2][3];
    #pragma unroll
    for (int ar = 0; ar < 2; ++ar)
        #pragma unroll
        for (int bc = 0; bc < 3; ++bc)
            acc[ar][bc] = (f32x4){0.f, 0.f, 0.f, 0.f};

    for (int ch = 0; ch < 8; ++ch) {
        const int j0 = ch * 128;
        __syncthreads();
        #pragma unroll
        for (int i = 0; i < 2; ++i) {
            int u = i * 256 + t;
            int row = u >> 4, uc = u & 15;
            const float* xp = &x[(size_t)(row0 + row) * HH + j0 + uc * 8];
            float4 a = *(const float4*)xp;
            float4 b = *(const float4*)(xp + 4);
            float fs[8] = {a.x, a.y, a.z, a.w, b.x, b.y, b.z, b.w};
            bf16x8 hv, lv;
            #pragma unroll
            for (int e = 0; e < 8; ++e) {
                ushort h = bf16rne(fs[e]);
                hv[e] = (short)h;
                lv[e] = (short)bf16rne(fs[e] - bf2f(h));
            }
            int su = uc ^ (row & 7);
            *(bf16x8*)(xhi + row * 128 + su * 8) = hv;
            *(bf16x8*)(xlo + row * 128 + su * 8) = lv;
        }
        __syncthreads();
        #pragma unroll
        for (int ks = 0; ks < 4; ++ks) {
            bf16x8 ah[2], al[2], bh[3], bl[3];
            #pragma unroll
            for (int ar = 0; ar < 2; ++ar) {
                int row = ar * 16 + (lane & 15);
                int su = (ks * 4 + (lane >> 4)) ^ (row & 7);
                ah[ar] = *(const bf16x8*)(xhi + row * 128 + su * 8);
                al[ar] = *(const bf16x8*)(xlo + row * 128 + su * 8);
            }
            const int koff = j0 + ks * 32 + (lane >> 4) * 8;
            #pragma unroll
            for (int bc = 0; bc < 3; ++bc) {
                int n = wid * 48 + bc * 16 + (lane & 15);
                bh[bc] = *(const bf16x8*)(Whi + (size_t)n * HH + koff);
                bl[bc] = *(const bf16x8*)(Wlo + (size_t)n * HH + koff);
            }
            #pragma unroll
            for (int ar = 0; ar < 2; ++ar)
                #pragma unroll
                for (int bc = 0; bc < 3; ++bc) {
                    acc[ar][bc] = MFMA16(ah[ar], bh[bc], acc[ar][bc]);
                    acc[ar][bc] = MFMA16(ah[ar], bl[bc], acc[ar][bc]);
                    acc[ar][bc] = MFMA16(al[ar], bh[bc], acc[ar][bc]);
                }
        }
    }
    __syncthreads();
    #pragma unroll
    for (int ar = 0; ar < 2; ++ar)
        #pragma unroll
        for (int bc = 0; bc < 3; ++bc) {
            int n = wid * 48 + bc * 16 + (lane & 15);
            #pragma unroll
            for (int r = 0; r < 4; ++r) {
                int row = ar * 16 + (lane >> 4) * 4 + r;
                ctile[row * 193 + n] = acc[ar][bc][r];
            }
        }
    __syncthreads();
    if (t < 96) {
        int mat = t >> 5, row = t & 31;
        float ss = 0.f;
        #pragma unroll 8
        for (int d = 0; d < 64; ++d) {
            float v = ctile[row * 193 + mat * 64 + d] + bsh[mat * 64 + d];
            ss = fmaf(v, v, ss);
        }
        rns[t] = 1.0f / fmaxf(sqrtf(ss), 1e-12f);
    }
    __syncthreads();
    #pragma unroll
    for (int i = 0; i < 24; ++i) {
        int idx = i * 256 + t;
        int row = idx / 192;
        int n = idx - row * 192;
        float v = (ctile[row * 193 + n] + bsh[n]) * rns[(n >> 6) * 32 + row];
        size_t off = (size_t)(row0 + row) * DD + (n & 63);
        if (n < 64) {
            ushort h = bf16rne(v);
            qh[off] = h; ql[off] = bf16rne(v - bf2f(h));
        } else if (n < 128) {
            ushort h = bf16rne(v);
            kh[off] = h; kl[off] = bf16rne(v - bf2f(h));
        } else {
            vw[off] = v;
        }
    }
}

// K2: score once. Per block: 32 q x 512 k (LDS 32KB), grid 8b*64qt*4ks = 2048.
// (R11 configuration — best measured.)
#define K_LOAD(H0,H1,H2,H3,L0,L1,L2,L3, KT) { \
    const ushort* kp = kh + (size_t)(b * SS + kbase + (KT) * 32 + qrow) * DD + kg; \
    const ushort* lp = kl + (size_t)(b * SS + kbase + (KT) * 32 + qrow) * DD + kg; \
    H0 = *(const bf16x8*)(kp);      L0 = *(const bf16x8*)(lp); \
    H1 = *(const bf16x8*)(kp + 16); L1 = *(const bf16x8*)(lp + 16); \
    H2 = *(const bf16x8*)(kp + 32); L2 = *(const bf16x8*)(lp + 32); \
    H3 = *(const bf16x8*)(kp + 48); L3 = *(const bf16x8*)(lp + 48); }

#define K_COMPUTE(H0,H1,H2,H3,L0,L1,L2,L3, KT) { \
    f32x16 acc = Z16; \
    acc = MFMA32(H0, qbh0, acc); acc = MFMA32(H0, qbl0, acc); acc = MFMA32(L0, qbh0, acc); \
    acc = MFMA32(H1, qbh1, acc); acc = MFMA32(H1, qbl1, acc); acc = MFMA32(L1, qbh1, acc); \
    acc = MFMA32(H2, qbh2, acc); acc = MFMA32(H2, qbl2, acc); acc = MFMA32(L2, qbh2, acc); \
    acc = MFMA32(H3, qbh3, acc); acc = MFMA32(H3, qbl3, acc); acc = MFMA32(L3, qbh3, acc); \
    const int kb = (w * 128 + (KT) * 32) * 2 + hi8; \
    uint2 wv; \
    wv.x = (uint)bfc(score_fn(acc[0]))  | ((uint)bfc(score_fn(acc[1]))  << 16); \
    wv.y = (uint)bfc(score_fn(acc[2]))  | ((uint)bfc(score_fn(acc[3]))  << 16); \
    *(uint2*)(ldsrow + ((kb +  0) ^ swq)) = wv; \
    wv.x = (uint)bfc(score_fn(acc[4]))  | ((uint)bfc(score_fn(acc[5]))  << 16); \
    wv.y = (uint)bfc(score_fn(acc[6]))  | ((uint)bfc(score_fn(acc[7]))  << 16); \
    *(uint2*)(ldsrow + ((kb + 16) ^ swq)) = wv; \
    wv.x = (uint)bfc(score_fn(acc[8]))  | ((uint)bfc(score_fn(acc[9]))  << 16); \
    wv.y = (uint)bfc(score_fn(acc[10])) | ((uint)bfc(score_fn(acc[11])) << 16); \
    *(uint2*)(ldsrow + ((kb + 32) ^ swq)) = wv; \
    wv.x = (uint)bfc(score_fn(acc[12])) | ((uint)bfc(score_fn(acc[13])) << 16); \
    wv.y = (uint)bfc(score_fn(acc[14])) | ((uint)bfc(score_fn(acc[15])) << 16); \
    *(uint2*)(ldsrow + ((kb + 48) ^ swq)) = wv; }

__global__ __launch_bounds__(256, 4) void k_score(
    const ushort* __restrict__ qh, const ushort* __restrict__ ql,
    const ushort* __restrict__ kh, const ushort* __restrict__ kl,
    ushort* __restrict__ scrS, float* __restrict__ colsum)
{
    __shared__ __align__(16) char slds[32 * 1024];   // [32 q][512 k] bf16, swizzled
    const int t = threadIdx.x;
    const int lane = t & 63;
    const int w = t >> 6;
    const int bid = blockIdx.x;
    const int b  = bid >> 8;
    const int q0 = ((bid >> 2) & 63) * 32;
    const int kgB = (bid & 3) * 512;
    const int kbase = kgB + w * 128;
    const int qrow = lane & 31;
    const int kg = (lane >> 5) * 8;
    const int hi8 = (lane >> 5) * 8;
    const int swq = (qrow & 15) << 3;
    char* ldsrow = slds + qrow * 1024;
    const f32x16 Z16 = {0.f,0.f,0.f,0.f,0.f,0.f,0.f,0.f,0.f,0.f,0.f,0.f,0.f,0.f,0.f,0.f};

    const size_t qoff = (size_t)(b * SS + q0 + qrow) * DD + kg;
    bf16x8 qbh0 = *(const bf16x8*)(qh + qoff);
    bf16x8 qbh1 = *(const bf16x8*)(qh + qoff + 16);
    bf16x8 qbh2 = *(const bf16x8*)(qh + qoff + 32);
    bf16x8 qbh3 = *(const bf16x8*)(qh + qoff + 48);
    bf16x8 qbl0 = *(const bf16x8*)(ql + qoff);
    bf16x8 qbl1 = *(const bf16x8*)(ql + qoff + 16);
    bf16x8 qbl2 = *(const bf16x8*)(ql + qoff + 32);
    bf16x8 qbl3 = *(const bf16x8*)(ql + qoff + 48);

    bf16x8 xh0, xh1, xh2, xh3, xl0, xl1, xl2, xl3;
    bf16x8 yh0, yh1, yh2, yh3, yl0, yl1, yl2, yl3;
    K_LOAD(xh0,xh1,xh2,xh3,xl0,xl1,xl2,xl3, 0)
    K_LOAD(yh0,yh1,yh2,yh3,yl0,yl1,yl2,yl3, 1)
    K_COMPUTE(xh0,xh1,xh2,xh3,xl0,xl1,xl2,xl3, 0)
    K_LOAD(xh0,xh1,xh2,xh3,xl0,xl1,xl2,xl3, 2)
    K_COMPUTE(yh0,yh1,yh2,yh3,yl0,yl1,yl2,yl3, 1)
    K_LOAD(yh0,yh1,yh2,yh3,yl0,yl1,yl2,yl3, 3)
    K_COMPUTE(xh0,xh1,xh2,xh3,xl0,xl1,xl2,xl3, 2)
    K_COMPUTE(yh0,yh1,yh2,yh3,yl0,yl1,yl2,yl3, 3)

    __syncthreads();
    // colsum over this block's 32 q rows: thread t handles k-local {2t, 2t+1}
    {
        float s0 = 0.f, s1 = 0.f;
        #pragma unroll 8
        for (int r = 0; r < 32; ++r) {
            uint d = *(const uint*)(slds + r * 1024 + ((t * 4) ^ ((r & 15) << 3)));
            s0 += bf2f((ushort)(d & 0xFFFFu));
            s1 += bf2f((ushort)(d >> 16));
        }
        atomicAdd(&colsum[b * SS + kgB + t * 2 + 0], s0);
        atomicAdd(&colsum[b * SS + kgB + t * 2 + 1], s1);
    }
    // coalesced global store: row r = t>>3, 8 threads/row, 16B chunks
    {
        const int r = t >> 3;
        const int swr = (r & 15) << 3;
        const char* lrow = slds + r * 1024;
        ushort* srowg = scrS + (size_t)(b * SS + q0 + r) * 4096 + 2048 + kgB;
        #pragma unroll
        for (int i = 0; i < 8; ++i) {
            int c = (t & 7) + i * 8;
            int lc = c * 16;
            uint2 a = *(const uint2*)(lrow + (lc ^ swr));
            uint2 bb = *(const uint2*)(lrow + ((lc + 8) ^ swr));
            uint4 v;
            v.x = a.x; v.y = a.y; v.z = bb.x; v.w = bb.y;
            *(uint4*)(srowg + c * 8) = v;
        }
    }
}

// K3b: c = colsum^-0.5; cvT build. Grid = 8b*32 = 256 blocks.
__global__ __launch_bounds__(256) void k_cvc(
    const float* __restrict__ vw, const float* __restrict__ colsum,
    ushort* __restrict__ cvT)
{
    __shared__ float vs[64][65];
    __shared__ float csh[64];
    const int t = threadIdx.x;
    const int b = blockIdx.x >> 5;
    const int k0 = (blockIdx.x & 31) * 64;
    #pragma unroll
    for (int i = 0; i < 4; ++i) {
        int idx = i * 256 + t;
        int r = idx >> 4, c4 = idx & 15;
        float4 v4 = *(const float4*)&vw[(size_t)(b * SS + k0 + r) * DD + c4 * 4];
        *(float4*)&vs[r][c4 * 4] = v4;
    }
    if (t < 64) csh[t] = 1.0f / sqrtf(colsum[b * SS + k0 + t]);
    __syncthreads();
    const int kk4 = (t & 15) * 4;
    #pragma unroll
    for (int jt = 0; jt < 4; ++jt) {
        int j = jt * 16 + (t >> 4);
        uint2 wv;
        wv.x = (uint)bfc(csh[kk4 + 0] * vs[kk4 + 0][j])
             | ((uint)bfc(csh[kk4 + 1] * vs[kk4 + 1][j]) << 16);
        wv.y = (uint)bfc(csh[kk4 + 2] * vs[kk4 + 2][j])
             | ((uint)bfc(csh[kk4 + 3] * vs[kk4 + 3][j]) << 16);
        *(uint2*)(cvT + ((size_t)b * NCV + j) * SS + k0 + kk4) = wv;
    }
    if (t < 16) {
        uint2 wv;
        wv.x = (uint)bfc(csh[t * 4 + 0]) | ((uint)bfc(csh[t * 4 + 1]) << 16);
        wv.y = (uint)bfc(csh[t * 4 + 2]) | ((uint)bfc(csh[t * 4 + 3]) << 16);
        *(uint2*)(cvT + ((size_t)b * NCV + 64) * SS + k0 + t * 4) = wv;
    }
}

// K4: fused N/D + probs per 16 q-rows. Grid = 8b*128qt = 1024, 256 thr (4 waves).
// Phase A: stream score rows (one 16B load = D operand AND N A-frag), 16x16 N-MFMA.
// Phase B: probs, ALL 16 rows in one register batch -> ONE barrier, 32-store burst.
__global__ __launch_bounds__(256, 4) void k_ndp(
    const ushort* __restrict__ scrS, const ushort* __restrict__ cvT,
    float* __restrict__ probs, float* __restrict__ out)
{
    __shared__ float nred[16][64];
    __shared__ float dPart[4][16];
    __shared__ float dInv[16];
    const int t = threadIdx.x;
    const int lane = t & 63;
    const int w = t >> 6;
    const int b = blockIdx.x >> 7;
    const int q0 = (blockIdx.x & 127) * 16;
    const int kbase = w * 512;
    const int qn = lane & 15;
    const int g = lane >> 4;

    ((float*)nred)[t] = 0.f; ((float*)nred)[t + 256] = 0.f;
    ((float*)nred)[t + 512] = 0.f; ((float*)nred)[t + 768] = 0.f;
    __syncthreads();

    const ushort* cslice = cvT + (size_t)b * NCV * SS;
    const ushort* cbrow = cslice + (size_t)64 * SS;

    float dacc = 0.f;
    f32x4 nacc[4];
    #pragma unroll
    for (int ct = 0; ct < 4; ++ct) nacc[ct] = (f32x4){0.f, 0.f, 0.f, 0.f};

    const ushort* sp = scrS + (size_t)(b * SS + q0 + qn) * 4096 + 2048 + kbase + g * 8;
    const ushort* cp = cbrow + kbase + g * 8;
    const ushort* p0 = cslice + (size_t)(0 * 16 + qn) * SS + kbase + g * 8;
    const ushort* p1 = cslice + (size_t)(1 * 16 + qn) * SS + kbase + g * 8;
    const ushort* p2 = cslice + (size_t)(2 * 16 + qn) * SS + kbase + g * 8;
    const ushort* p3 = cslice + (size_t)(3 * 16 + qn) * SS + kbase + g * 8;

    #pragma unroll 4
    for (int ch = 0; ch < 16; ++ch) {
        bf16x8 s8 = *(const bf16x8*)sp;
        bf16x8 c8 = *(const bf16x8*)cp;
        bf16x8 b0 = *(const bf16x8*)p0;
        bf16x8 b1 = *(const bf16x8*)p1;
        bf16x8 b2 = *(const bf16x8*)p2;
        bf16x8 b3 = *(const bf16x8*)p3;
        #pragma unroll
        for (int e = 0; e < 8; ++e)
            dacc = fmaf(bf2f((ushort)s8[e]), bf2f((ushort)c8[e]), dacc);
        nacc[0] = MFMA16(s8, b0, nacc[0]);
        nacc[1] = MFMA16(s8, b1, nacc[1]);
        nacc[2] = MFMA16(s8, b2, nacc[2]);
        nacc[3] = MFMA16(s8, b3, nacc[3]);
        sp += 32; cp += 32; p0 += 32; p1 += 32; p2 += 32; p3 += 32;
    }
    {
        float d = dacc;
        d += __shfl_xor(d, 16, 64);
        d += __shfl_xor(d, 32, 64);
        if (lane < 16) dPart[w][lane] = d;
    }
    __syncthreads();
    if (t < 16) dInv[t] = 1.0f / (dPart[0][t] + dPart[1][t] + dPart[2][t] + dPart[3][t]);
    #pragma unroll
    for (int ct = 0; ct < 4; ++ct)
        #pragma unroll
        for (int r = 0; r < 4; ++r)
            atomicAdd(&nred[g * 4 + r][ct * 16 + qn], nacc[ct][r]);
    __syncthreads();
    {
        int q = t >> 4, c4 = (t & 15) * 4;
        float di = dInv[q];
        float4 o;
        o.x = nred[q][c4] * di;     o.y = nred[q][c4 + 1] * di;
        o.z = nred[q][c4 + 2] * di; o.w = nred[q][c4 + 3] * di;
        *(float4*)&out[(size_t)(b * SS + q0 + q) * DD + c4] = o;
    }
    // Phase B: probs = s*c*dInv. ALL 16 rows to registers, ONE barrier, store burst.
    float cf[8];
    {
        bf16x8 c8 = *(const bf16x8*)(cbrow + t * 8);
        #pragma unroll
        for (int e = 0; e < 8; ++e) cf[e] = bf2f((ushort)c8[e]);
    }
    bf16x8 s[16];
    float dl[16];
    #pragma unroll
    for (int j = 0; j < 16; ++j) {
        s[j] = *(const bf16x8*)(scrS + (size_t)(b * SS + q0 + j) * 4096 + 2048 + t * 8);
        dl[j] = dInv[j];
    }
    __syncthreads();   // all reads of these 16 rows done before their writes
    #pragma unroll
    for (int j = 0; j < 16; ++j) {
        f32x4 o0, o1;
        o0[0] = bf2f((ushort)s[j][0]) * cf[0] * dl[j];
        o0[1] = bf2f((ushort)s[j][1]) * cf[1] * dl[j];
        o0[2] = bf2f((ushort)s[j][2]) * cf[2] * dl[j];
        o0[3] = bf2f((ushort)s[j][3]) * cf[3] * dl[j];
        o1[0] = bf2f((ushort)s[j][4]) * cf[4] * dl[j];
        o1[1] = bf2f((ushort)s[j][5]) * cf[5] * dl[j];
        o1[2] = bf2f((ushort)s[j][6]) * cf[6] * dl[j];
        o1[3] = bf2f((ushort)s[j][7]) * cf[7] * dl[j];
        float* prow = probs + (size_t)(b * SS + q0 + j) * SS + t * 8;
        __builtin_nontemporal_store(o0, (f32x4*)prow);
        __builtin_nontemporal_store(o1, (f32x4*)(prow + 4));
    }
}

extern "C" void kernel_launch(void* const* d_in, const int* in_sizes, int n_in,
                              void* d_out, int out_size, void* d_ws, size_t ws_size,
                              hipStream_t stream)
{
    const float* x  = (const float*)d_in[0];
    const float* Wq = (const float*)d_in[1];
    const float* bq = (const float*)d_in[2];
    const float* Wk = (const float*)d_in[3];
    const float* bk = (const float*)d_in[4];
    const float* Wv = (const float*)d_in[5];
    const float* bv = (const float*)d_in[6];

    float* out   = (float*)d_out;                       // [8,2048,64]
    float* probs = out + (size_t)BB * SS * DD;          // [8,2048,2048]
    ushort* scrS = (ushort*)probs;                      // score bf16 in row upper halves

    const size_t NQ = (size_t)BB * SS * DD;
    ushort* qh    = (ushort*)d_ws;
    ushort* ql    = qh + NQ;
    ushort* kh    = ql + NQ;
    ushort* kl    = kh + NQ;
    float*  vw    = (float*)(kl + NQ);
    float*  colsum = vw + NQ;
    ushort* cvT   = (ushort*)(colsum + BB * SS);
    ushort* Whi   = cvT + (size_t)BB * NCV * SS;
    ushort* Wlo   = Whi + (size_t)192 * HH;
    float*  bcat  = (float*)(Wlo + (size_t)192 * HH);

    hipMemsetAsync(colsum, 0, BB * SS * sizeof(float), stream);
    k_prep  <<<192, 256, 0, stream>>>(Wq, Wk, Wv, bq, bk, bv, Whi, Wlo, bcat);
    k_projmm<<<512, 256, 0, stream>>>(x, Whi, Wlo, bcat, qh, ql, kh, kl, vw);
    k_score <<<2048, 256, 0, stream>>>(qh, ql, kh, kl, scrS, colsum);
    k_cvc   <<<256, 256, 0, stream>>>(vw, colsum, cvT);
    k_ndp   <<<1024, 256, 0, stream>>>(scrS, cvT, probs, out);
}

// Round 16
// 188.361 us; speedup vs baseline: 1.1175x; 1.0446x over previous
//
#include <hip/hip_runtime.h>
#include <hip/hip_bf16.h>
#include <math.h>

#define BB 8
#define SS 2048
#define HH 1024
#define DD 64
#define NCV 65

typedef __attribute__((ext_vector_type(8))) short bf16x8;
typedef __attribute__((ext_vector_type(4))) float f32x4;
typedef __attribute__((ext_vector_type(16))) float f32x16;

#define MFMA16(a, b, c) __builtin_amdgcn_mfma_f32_16x16x32_bf16(a, b, c, 0, 0, 0)
#define MFMA32(a, b, c) __builtin_amdgcn_mfma_f32_32x32x16_bf16(a, b, c, 0, 0, 0)

__device__ __forceinline__ ushort bf16rne(float f) {
    uint u = __float_as_uint(f);
    uint r = (u + 0x7FFFu + ((u >> 16) & 1u)) >> 16;
    return (ushort)r;
}
__device__ __forceinline__ ushort bfc(float f) {
    __hip_bfloat16 h = __float2bfloat16(f);
    return *reinterpret_cast<ushort*>(&h);
}
__device__ __forceinline__ float bf2f(ushort h) {
    return __uint_as_float(((uint)h) << 16);
}

// score = (1 + acos(clip(cos)))^-65.5
__device__ __forceinline__ float score_fn(float cosv) {
    float ax = fminf(fabsf(cosv), 1.0f - 1e-7f);
    float p = fmaf(ax, -0.0012624911f, 0.0066700901f);
    p = fmaf(ax, p, -0.0170881256f);
    p = fmaf(ax, p, 0.0308918810f);
    p = fmaf(ax, p, -0.0501743046f);
    p = fmaf(ax, p, 0.0889789874f);
    p = fmaf(ax, p, -0.2145988016f);
    p = fmaf(ax, p, 1.5707963050f);
    float r = sqrtf(1.0f - ax) * p;
    float g = (cosv >= 0.0f) ? r : (3.14159265358979f - r);
    return exp2f(-65.5f * log2f(1.0f + g));
}

// K0: split W into bf16 hi/lo. Also zeroes colsum (replaces hipMemsetAsync launch).
__global__ __launch_bounds__(256) void k_prep(
    const float* __restrict__ Wq, const float* __restrict__ Wk, const float* __restrict__ Wv,
    const float* __restrict__ bq, const float* __restrict__ bk, const float* __restrict__ bv,
    ushort* __restrict__ Whi, ushort* __restrict__ Wlo, float* __restrict__ bcat,
    float* __restrict__ colsum)
{
    const int n = blockIdx.x;
    const int m = n >> 6, d = n & 63;
    const float* W = (m == 0) ? Wq : (m == 1 ? Wk : Wv);
    #pragma unroll
    for (int i = 0; i < 4; ++i) {
        int j = i * 256 + threadIdx.x;
        float f = W[(size_t)j * DD + d];
        ushort h = bf16rne(f);
        Whi[(size_t)n * HH + j] = h;
        Wlo[(size_t)n * HH + j] = bf16rne(f - bf2f(h));
    }
    if (n == 0 && threadIdx.x < 192) {
        int t = threadIdx.x, mm = t >> 6, dd = t & 63;
        const float* b = (mm == 0) ? bq : (mm == 1 ? bk : bv);
        bcat[t] = b[dd];
    }
    if (n < 64) colsum[n * 256 + threadIdx.x] = 0.f;   // 64*256 = 16384 = BB*SS
}

// K1: q,k,v = l2norm(x @ W + b) via split-bf16 MFMA.
__global__ __launch_bounds__(256) void k_projmm(
    const float* __restrict__ x, const ushort* __restrict__ Whi,
    const ushort* __restrict__ Wlo, const float* __restrict__ bcat,
    ushort* __restrict__ qh, ushort* __restrict__ ql,
    ushort* __restrict__ kh, ushort* __restrict__ kl,
    float* __restrict__ vw)
{
    __shared__ __align__(16) char smem[32 * 193 * 4];
    __shared__ float rns[96];
    __shared__ float bsh[192];
    ushort* xhi = (ushort*)smem;
    ushort* xlo = xhi + 32 * 128;
    float* ctile = (float*)smem;

    const int t = threadIdx.x;
    const int lane = t & 63;
    const int wid = t >> 6;
    const int row0 = blockIdx.x * 32;
    if (t < 192) bsh[t] = bcat[t];

    f32x4 acc[2][3];
    #pragma unroll
    for (int ar = 0; ar < 2; ++ar)
        #pragma unroll
        for (int bc = 0; bc < 3; ++bc)
            acc[ar][bc] = (f32x4){0.f, 0.f, 0.f, 0.f};

    for (int ch = 0; ch < 8; ++ch) {
        const int j0 = ch * 128;
        __syncthreads();
        #pragma unroll
        for (int i = 0; i < 2; ++i) {
            int u = i * 256 + t;
            int row = u >> 4, uc = u & 15;
            const float* xp = &x[(size_t)(row0 + row) * HH + j0 + uc * 8];
            float4 a = *(const float4*)xp;
            float4 b = *(const float4*)(xp + 4);
            float fs[8] = {a.x, a.y, a.z, a.w, b.x, b.y, b.z, b.w};
            bf16x8 hv, lv;
            #pragma unroll
            for (int e = 0; e < 8; ++e) {
                ushort h = bf16rne(fs[e]);
                hv[e] = (short)h;
                lv[e] = (short)bf16rne(fs[e] - bf2f(h));
            }
            int su = uc ^ (row & 7);
            *(bf16x8*)(xhi + row * 128 + su * 8) = hv;
            *(bf16x8*)(xlo + row * 128 + su * 8) = lv;
        }
        __syncthreads();
        #pragma unroll
        for (int ks = 0; ks < 4; ++ks) {
            bf16x8 ah[2], al[2], bh[3], bl[3];
            #pragma unroll
            for (int ar = 0; ar < 2; ++ar) {
                int row = ar * 16 + (lane & 15);
                int su = (ks * 4 + (lane >> 4)) ^ (row & 7);
                ah[ar] = *(const bf16x8*)(xhi + row * 128 + su * 8);
                al[ar] = *(const bf16x8*)(xlo + row * 128 + su * 8);
            }
            const int koff = j0 + ks * 32 + (lane >> 4) * 8;
            #pragma unroll
            for (int bc = 0; bc < 3; ++bc) {
                int n = wid * 48 + bc * 16 + (lane & 15);
                bh[bc] = *(const bf16x8*)(Whi + (size_t)n * HH + koff);
                bl[bc] = *(const bf16x8*)(Wlo + (size_t)n * HH + koff);
            }
            #pragma unroll
            for (int ar = 0; ar < 2; ++ar)
                #pragma unroll
                for (int bc = 0; bc < 3; ++bc) {
                    acc[ar][bc] = MFMA16(ah[ar], bh[bc], acc[ar][bc]);
                    acc[ar][bc] = MFMA16(ah[ar], bl[bc], acc[ar][bc]);
                    acc[ar][bc] = MFMA16(al[ar], bh[bc], acc[ar][bc]);
                }
        }
    }
    __syncthreads();
    #pragma unroll
    for (int ar = 0; ar < 2; ++ar)
        #pragma unroll
        for (int bc = 0; bc < 3; ++bc) {
            int n = wid * 48 + bc * 16 + (lane & 15);
            #pragma unroll
            for (int r = 0; r < 4; ++r) {
                int row = ar * 16 + (lane >> 4) * 4 + r;
                ctile[row * 193 + n] = acc[ar][bc][r];
            }
        }
    __syncthreads();
    if (t < 96) {
        int mat = t >> 5, row = t & 31;
        float ss = 0.f;
        #pragma unroll 8
        for (int d = 0; d < 64; ++d) {
            float v = ctile[row * 193 + mat * 64 + d] + bsh[mat * 64 + d];
            ss = fmaf(v, v, ss);
        }
        rns[t] = 1.0f / fmaxf(sqrtf(ss), 1e-12f);
    }
    __syncthreads();
    #pragma unroll
    for (int i = 0; i < 24; ++i) {
        int idx = i * 256 + t;
        int row = idx / 192;
        int n = idx - row * 192;
        float v = (ctile[row * 193 + n] + bsh[n]) * rns[(n >> 6) * 32 + row];
        size_t off = (size_t)(row0 + row) * DD + (n & 63);
        if (n < 64) {
            ushort h = bf16rne(v);
            qh[off] = h; ql[off] = bf16rne(v - bf2f(h));
        } else if (n < 128) {
            ushort h = bf16rne(v);
            kh[off] = h; kl[off] = bf16rne(v - bf2f(h));
        } else {
            vw[off] = v;
        }
    }
}

// K2: score once. Per block: 32 q x 512 k (LDS 32KB), grid 8b*64qt*4ks = 2048.
// (R11 configuration — best measured.)
#define K_LOAD(H0,H1,H2,H3,L0,L1,L2,L3, KT) { \
    const ushort* kp = kh + (size_t)(b * SS + kbase + (KT) * 32 + qrow) * DD + kg; \
    const ushort* lp = kl + (size_t)(b * SS + kbase + (KT) * 32 + qrow) * DD + kg; \
    H0 = *(const bf16x8*)(kp);      L0 = *(const bf16x8*)(lp); \
    H1 = *(const bf16x8*)(kp + 16); L1 = *(const bf16x8*)(lp + 16); \
    H2 = *(const bf16x8*)(kp + 32); L2 = *(const bf16x8*)(lp + 32); \
    H3 = *(const bf16x8*)(kp + 48); L3 = *(const bf16x8*)(lp + 48); }

#define K_COMPUTE(H0,H1,H2,H3,L0,L1,L2,L3, KT) { \
    f32x16 acc = Z16; \
    acc = MFMA32(H0, qbh0, acc); acc = MFMA32(H0, qbl0, acc); acc = MFMA32(L0, qbh0, acc); \
    acc = MFMA32(H1, qbh1, acc); acc = MFMA32(H1, qbl1, acc); acc = MFMA32(L1, qbh1, acc); \
    acc = MFMA32(H2, qbh2, acc); acc = MFMA32(H2, qbl2, acc); acc = MFMA32(L2, qbh2, acc); \
    acc = MFMA32(H3, qbh3, acc); acc = MFMA32(H3, qbl3, acc); acc = MFMA32(L3, qbh3, acc); \
    const int kb = (w * 128 + (KT) * 32) * 2 + hi8; \
    uint2 wv; \
    wv.x = (uint)bfc(score_fn(acc[0]))  | ((uint)bfc(score_fn(acc[1]))  << 16); \
    wv.y = (uint)bfc(score_fn(acc[2]))  | ((uint)bfc(score_fn(acc[3]))  << 16); \
    *(uint2*)(ldsrow + ((kb +  0) ^ swq)) = wv; \
    wv.x = (uint)bfc(score_fn(acc[4]))  | ((uint)bfc(score_fn(acc[5]))  << 16); \
    wv.y = (uint)bfc(score_fn(acc[6]))  | ((uint)bfc(score_fn(acc[7]))  << 16); \
    *(uint2*)(ldsrow + ((kb + 16) ^ swq)) = wv; \
    wv.x = (uint)bfc(score_fn(acc[8]))  | ((uint)bfc(score_fn(acc[9]))  << 16); \
    wv.y = (uint)bfc(score_fn(acc[10])) | ((uint)bfc(score_fn(acc[11])) << 16); \
    *(uint2*)(ldsrow + ((kb + 32) ^ swq)) = wv; \
    wv.x = (uint)bfc(score_fn(acc[12])) | ((uint)bfc(score_fn(acc[13])) << 16); \
    wv.y = (uint)bfc(score_fn(acc[14])) | ((uint)bfc(score_fn(acc[15])) << 16); \
    *(uint2*)(ldsrow + ((kb + 48) ^ swq)) = wv; }

__global__ __launch_bounds__(256, 4) void k_score(
    const ushort* __restrict__ qh, const ushort* __restrict__ ql,
    const ushort* __restrict__ kh, const ushort* __restrict__ kl,
    ushort* __restrict__ scrS, float* __restrict__ colsum)
{
    __shared__ __align__(16) char slds[32 * 1024];   // [32 q][512 k] bf16, swizzled
    const int t = threadIdx.x;
    const int lane = t & 63;
    const int w = t >> 6;
    const int bid = blockIdx.x;
    const int b  = bid >> 8;
    const int q0 = ((bid >> 2) & 63) * 32;
    const int kgB = (bid & 3) * 512;
    const int kbase = kgB + w * 128;
    const int qrow = lane & 31;
    const int kg = (lane >> 5) * 8;
    const int hi8 = (lane >> 5) * 8;
    const int swq = (qrow & 15) << 3;
    char* ldsrow = slds + qrow * 1024;
    const f32x16 Z16 = {0.f,0.f,0.f,0.f,0.f,0.f,0.f,0.f,0.f,0.f,0.f,0.f,0.f,0.f,0.f,0.f};

    const size_t qoff = (size_t)(b * SS + q0 + qrow) * DD + kg;
    bf16x8 qbh0 = *(const bf16x8*)(qh + qoff);
    bf16x8 qbh1 = *(const bf16x8*)(qh + qoff + 16);
    bf16x8 qbh2 = *(const bf16x8*)(qh + qoff + 32);
    bf16x8 qbh3 = *(const bf16x8*)(qh + qoff + 48);
    bf16x8 qbl0 = *(const bf16x8*)(ql + qoff);
    bf16x8 qbl1 = *(const bf16x8*)(ql + qoff + 16);
    bf16x8 qbl2 = *(const bf16x8*)(ql + qoff + 32);
    bf16x8 qbl3 = *(const bf16x8*)(ql + qoff + 48);

    bf16x8 xh0, xh1, xh2, xh3, xl0, xl1, xl2, xl3;
    bf16x8 yh0, yh1, yh2, yh3, yl0, yl1, yl2, yl3;
    K_LOAD(xh0,xh1,xh2,xh3,xl0,xl1,xl2,xl3, 0)
    K_LOAD(yh0,yh1,yh2,yh3,yl0,yl1,yl2,yl3, 1)
    K_COMPUTE(xh0,xh1,xh2,xh3,xl0,xl1,xl2,xl3, 0)
    K_LOAD(xh0,xh1,xh2,xh3,xl0,xl1,xl2,xl3, 2)
    K_COMPUTE(yh0,yh1,yh2,yh3,yl0,yl1,yl2,yl3, 1)
    K_LOAD(yh0,yh1,yh2,yh3,yl0,yl1,yl2,yl3, 3)
    K_COMPUTE(xh0,xh1,xh2,xh3,xl0,xl1,xl2,xl3, 2)
    K_COMPUTE(yh0,yh1,yh2,yh3,yl0,yl1,yl2,yl3, 3)

    __syncthreads();
    // colsum over this block's 32 q rows: thread t handles k-local {2t, 2t+1}
    {
        float s0 = 0.f, s1 = 0.f;
        #pragma unroll 8
        for (int r = 0; r < 32; ++r) {
            uint d = *(const uint*)(slds + r * 1024 + ((t * 4) ^ ((r & 15) << 3)));
            s0 += bf2f((ushort)(d & 0xFFFFu));
            s1 += bf2f((ushort)(d >> 16));
        }
        atomicAdd(&colsum[b * SS + kgB + t * 2 + 0], s0);
        atomicAdd(&colsum[b * SS + kgB + t * 2 + 1], s1);
    }
    // coalesced global store: row r = t>>3, 8 threads/row, 16B chunks
    {
        const int r = t >> 3;
        const int swr = (r & 15) << 3;
        const char* lrow = slds + r * 1024;
        ushort* srowg = scrS + (size_t)(b * SS + q0 + r) * 4096 + 2048 + kgB;
        #pragma unroll
        for (int i = 0; i < 8; ++i) {
            int c = (t & 7) + i * 8;
            int lc = c * 16;
            uint2 a = *(const uint2*)(lrow + (lc ^ swr));
            uint2 bb = *(const uint2*)(lrow + ((lc + 8) ^ swr));
            uint4 v;
            v.x = a.x; v.y = a.y; v.z = bb.x; v.w = bb.y;
            *(uint4*)(srowg + c * 8) = v;
        }
    }
}

// K3b: c = colsum^-0.5; cvT build. Grid = 8b*32 = 256 blocks.
__global__ __launch_bounds__(256) void k_cvc(
    const float* __restrict__ vw, const float* __restrict__ colsum,
    ushort* __restrict__ cvT)
{
    __shared__ float vs[64][65];
    __shared__ float csh[64];
    const int t = threadIdx.x;
    const int b = blockIdx.x >> 5;
    const int k0 = (blockIdx.x & 31) * 64;
    #pragma unroll
    for (int i = 0; i < 4; ++i) {
        int idx = i * 256 + t;
        int r = idx >> 4, c4 = idx & 15;
        float4 v4 = *(const float4*)&vw[(size_t)(b * SS + k0 + r) * DD + c4 * 4];
        *(float4*)&vs[r][c4 * 4] = v4;
    }
    if (t < 64) csh[t] = 1.0f / sqrtf(colsum[b * SS + k0 + t]);
    __syncthreads();
    const int kk4 = (t & 15) * 4;
    #pragma unroll
    for (int jt = 0; jt < 4; ++jt) {
        int j = jt * 16 + (t >> 4);
        uint2 wv;
        wv.x = (uint)bfc(csh[kk4 + 0] * vs[kk4 + 0][j])
             | ((uint)bfc(csh[kk4 + 1] * vs[kk4 + 1][j]) << 16);
        wv.y = (uint)bfc(csh[kk4 + 2] * vs[kk4 + 2][j])
             | ((uint)bfc(csh[kk4 + 3] * vs[kk4 + 3][j]) << 16);
        *(uint2*)(cvT + ((size_t)b * NCV + j) * SS + k0 + kk4) = wv;
    }
    if (t < 16) {
        uint2 wv;
        wv.x = (uint)bfc(csh[t * 4 + 0]) | ((uint)bfc(csh[t * 4 + 1]) << 16);
        wv.y = (uint)bfc(csh[t * 4 + 2]) | ((uint)bfc(csh[t * 4 + 3]) << 16);
        *(uint2*)(cvT + ((size_t)b * NCV + 64) * SS + k0 + t * 4) = wv;
    }
}

// K4: fused N/D + probs per 16 q-rows. Grid = 8b*128qt = 1024, 256 thr (4 waves).
// Phase A: stream score rows (one 16B load = D operand AND N A-frag), 16x16 N-MFMA.
// Phase B: probs in 4-row register batches with one barrier each; nontemporal stores.
__global__ __launch_bounds__(256, 4) void k_ndp(
    const ushort* __restrict__ scrS, const ushort* __restrict__ cvT,
    float* __restrict__ probs, float* __restrict__ out)
{
    __shared__ float nred[16][64];
    __shared__ float dPart[4][16];
    __shared__ float dInv[16];
    const int t = threadIdx.x;
    const int lane = t & 63;
    const int w = t >> 6;
    const int b = blockIdx.x >> 7;
    const int q0 = (blockIdx.x & 127) * 16;
    const int kbase = w * 512;
    const int qn = lane & 15;
    const int g = lane >> 4;

    ((float*)nred)[t] = 0.f; ((float*)nred)[t + 256] = 0.f;
    ((float*)nred)[t + 512] = 0.f; ((float*)nred)[t + 768] = 0.f;
    __syncthreads();

    const ushort* cslice = cvT + (size_t)b * NCV * SS;
    const ushort* cbrow = cslice + (size_t)64 * SS;

    float dacc = 0.f;
    f32x4 nacc[4];
    #pragma unroll
    for (int ct = 0; ct < 4; ++ct) nacc[ct] = (f32x4){0.f, 0.f, 0.f, 0.f};

    const ushort* sp = scrS + (size_t)(b * SS + q0 + qn) * 4096 + 2048 + kbase + g * 8;
    const ushort* cp = cbrow + kbase + g * 8;
    const ushort* p0 = cslice + (size_t)(0 * 16 + qn) * SS + kbase + g * 8;
    const ushort* p1 = cslice + (size_t)(1 * 16 + qn) * SS + kbase + g * 8;
    const ushort* p2 = cslice + (size_t)(2 * 16 + qn) * SS + kbase + g * 8;
    const ushort* p3 = cslice + (size_t)(3 * 16 + qn) * SS + kbase + g * 8;

    #pragma unroll 4
    for (int ch = 0; ch < 16; ++ch) {
        bf16x8 s8 = *(const bf16x8*)sp;
        bf16x8 c8 = *(const bf16x8*)cp;
        bf16x8 b0 = *(const bf16x8*)p0;
        bf16x8 b1 = *(const bf16x8*)p1;
        bf16x8 b2 = *(const bf16x8*)p2;
        bf16x8 b3 = *(const bf16x8*)p3;
        #pragma unroll
        for (int e = 0; e < 8; ++e)
            dacc = fmaf(bf2f((ushort)s8[e]), bf2f((ushort)c8[e]), dacc);
        nacc[0] = MFMA16(s8, b0, nacc[0]);
        nacc[1] = MFMA16(s8, b1, nacc[1]);
        nacc[2] = MFMA16(s8, b2, nacc[2]);
        nacc[3] = MFMA16(s8, b3, nacc[3]);
        sp += 32; cp += 32; p0 += 32; p1 += 32; p2 += 32; p3 += 32;
    }
    {
        float d = dacc;
        d += __shfl_xor(d, 16, 64);
        d += __shfl_xor(d, 32, 64);
        if (lane < 16) dPart[w][lane] = d;
    }
    __syncthreads();
    if (t < 16) dInv[t] = 1.0f / (dPart[0][t] + dPart[1][t] + dPart[2][t] + dPart[3][t]);
    #pragma unroll
    for (int ct = 0; ct < 4; ++ct)
        #pragma unroll
        for (int r = 0; r < 4; ++r)
            atomicAdd(&nred[g * 4 + r][ct * 16 + qn], nacc[ct][r]);
    __syncthreads();
    {
        int q = t >> 4, c4 = (t & 15) * 4;
        float di = dInv[q];
        float4 o;
        o.x = nred[q][c4] * di;     o.y = nred[q][c4 + 1] * di;
        o.z = nred[q][c4 + 2] * di; o.w = nred[q][c4 + 3] * di;
        *(float4*)&out[(size_t)(b * SS + q0 + q) * DD + c4] = o;
    }
    // Phase B: probs = s*c*dInv. 4-row register batches; thread t covers k=t*8..+7.
    float cf[8];
    {
        bf16x8 c8 = *(const bf16x8*)(cbrow + t * 8);
        #pragma unroll
        for (int e = 0; e < 8; ++e) cf[e] = bf2f((ushort)c8[e]);
    }
    #pragma unroll
    for (int rb = 0; rb < 4; ++rb) {
        bf16x8 s[4];
        float dl[4];
        #pragma unroll
        for (int j = 0; j < 4; ++j) {
            int row = rb * 4 + j;
            s[j] = *(const bf16x8*)(scrS + (size_t)(b * SS + q0 + row) * 4096 + 2048 + t * 8);
            dl[j] = dInv[row];
        }
        __syncthreads();   // all reads of these 4 rows done before their writes
        #pragma unroll
        for (int j = 0; j < 4; ++j) {
            f32x4 o0, o1;
            o0[0] = bf2f((ushort)s[j][0]) * cf[0] * dl[j];
            o0[1] = bf2f((ushort)s[j][1]) * cf[1] * dl[j];
            o0[2] = bf2f((ushort)s[j][2]) * cf[2] * dl[j];
            o0[3] = bf2f((ushort)s[j][3]) * cf[3] * dl[j];
            o1[0] = bf2f((ushort)s[j][4]) * cf[4] * dl[j];
            o1[1] = bf2f((ushort)s[j][5]) * cf[5] * dl[j];
            o1[2] = bf2f((ushort)s[j][6]) * cf[6] * dl[j];
            o1[3] = bf2f((ushort)s[j][7]) * cf[7] * dl[j];
            float* prow = probs + (size_t)(b * SS + q0 + rb * 4 + j) * SS + t * 8;
            __builtin_nontemporal_store(o0, (f32x4*)prow);
            __builtin_nontemporal_store(o1, (f32x4*)(prow + 4));
        }
    }
}

extern "C" void kernel_launch(void* const* d_in, const int* in_sizes, int n_in,
                              void* d_out, int out_size, void* d_ws, size_t ws_size,
                              hipStream_t stream)
{
    const float* x  = (const float*)d_in[0];
    const float* Wq = (const float*)d_in[1];
    const float* bq = (const float*)d_in[2];
    const float* Wk = (const float*)d_in[3];
    const float* bk = (const float*)d_in[4];
    const float* Wv = (const float*)d_in[5];
    const float* bv = (const float*)d_in[6];

    float* out   = (float*)d_out;                       // [8,2048,64]
    float* probs = out + (size_t)BB * SS * DD;          // [8,2048,2048]
    ushort* scrS = (ushort*)probs;                      // score bf16 in row upper halves

    const size_t NQ = (size_t)BB * SS * DD;
    ushort* qh    = (ushort*)d_ws;
    ushort* ql    = qh + NQ;
    ushort* kh    = ql + NQ;
    ushort* kl    = kh + NQ;
    float*  vw    = (float*)(kl + NQ);
    float*  colsum = vw + NQ;
    ushort* cvT   = (ushort*)(colsum + BB * SS);
    ushort* Whi   = cvT + (size_t)BB * NCV * SS;
    ushort* Wlo   = Whi + (size_t)192 * HH;
    float*  bcat  = (float*)(Wlo + (size_t)192 * HH);

    k_prep  <<<192, 256, 0, stream>>>(Wq, Wk, Wv, bq, bk, bv, Whi, Wlo, bcat, colsum);
    k_projmm<<<512, 256, 0, stream>>>(x, Whi, Wlo, bcat, qh, ql, kh, kl, vw);
    k_score <<<2048, 256, 0, stream>>>(qh, ql, kh, kl, scrS, colsum);
    k_cvc   <<<256, 256, 0, stream>>>(vw, colsum, cvT);
    k_ndp   <<<1024, 256, 0, stream>>>(scrS, cvT, probs, out);
}